// Round 2
// baseline (8341.061 us; speedup 1.0000x reference)
//
#include <hip/hip_runtime.h>
#include <cstdint>

typedef unsigned short u16;
typedef short s16x8 __attribute__((ext_vector_type(8)));
typedef u16   u16x4 __attribute__((ext_vector_type(4)));
typedef u16   u16x8 __attribute__((ext_vector_type(8)));
typedef float f32x4 __attribute__((ext_vector_type(4)));

__device__ __forceinline__ float bf2f(u16 u){
  union { unsigned int i; float f; } v; v.i = ((unsigned int)u) << 16; return v.f;
}
__device__ __forceinline__ u16 f2bf(float f){
  union { float f; unsigned int i; } v; v.f = f;
  unsigned int r = v.i + 0x7fffu + ((v.i >> 16) & 1u);
  return (u16)(r >> 16);
}

// ---------------- fp32 -> bf16 cast (vectorized), n multiple of 4 ----------------
__global__ __launch_bounds__(256) void castf2b_v4(const float* __restrict__ src,
                                                  u16* __restrict__ dst, int n4){
  int i = blockIdx.x * 256 + threadIdx.x;
  if (i >= n4) return;
  f32x4 v = *(const f32x4*)(src + i * 4);
  u16x4 o;
  o[0] = f2bf(v[0]); o[1] = f2bf(v[1]); o[2] = f2bf(v[2]); o[3] = f2bf(v[3]);
  *(u16x4*)(dst + i * 4) = o;
}

// ---------------- positional encoding (fp32) ----------------
__global__ __launch_bounds__(256) void pe_kernel(float* __restrict__ pe){
  int idx = blockIdx.x * 256 + threadIdx.x;       // 512*512
  int t = idx >> 9, h = idx & 511;
  int i2 = h >> 1;
  float freq = expf((float)(2 * i2) * (-9.210340371976184f / 512.0f));
  float a = (float)t * freq;
  pe[idx] = (h & 1) ? cosf(a) : sinf(a);
}

// ---------------- transpose+cast conv_w (C,D,K) fp32 -> (K*D, C) bf16 ----------------
__global__ __launch_bounds__(256) void convw_t_kernel(const float* __restrict__ w, u16* __restrict__ wt){
  int idx = blockIdx.x * 256 + threadIdx.x;       // 2048*512, idx = n*512 + c
  int n = idx >> 9, c = idx & 511;                // n = k*512 + d
  int k = n >> 9, d = n & 511;
  wt[idx] = f2bf(w[c * 2048 + d * 4 + k]);
}

// ---------------- x = query_emb + pe (fp32 residual stream) ----------------
__global__ __launch_bounds__(256) void initx_kernel(const float* __restrict__ qe,
                                                    const float* __restrict__ pe,
                                                    float* __restrict__ x){
  int idx = blockIdx.x * 256 + threadIdx.x;       // 32*512*512
  int th = idx & (512 * 512 - 1);
  x[idx] = qe[th] + pe[th];
}

// ---------------- mem[b, s*4+k, d] = convlin[b*128+s, k*512+d] + conv_b[d] + pe ----------------
__global__ __launch_bounds__(256) void mem_kernel(const u16* __restrict__ lin,
                                                  const float* __restrict__ cb,
                                                  const float* __restrict__ pe,
                                                  u16* __restrict__ mem){
  int idx = blockIdx.x * 256 + threadIdx.x;       // 32*512*512
  int d = idx & 511;
  int t = (idx >> 9) & 511;
  int b = idx >> 18;
  int s = t >> 2, k = t & 3;
  float v = bf2f(lin[(size_t)(b * 128 + s) * 2048 + k * 512 + d]) + cb[d] + pe[t * 512 + d];
  mem[idx] = f2bf(v);
}

// ---------------- cast fp32 -> bf16 ----------------
__global__ __launch_bounds__(256) void cast_kernel(const float* __restrict__ x, u16* __restrict__ o){
  int idx = blockIdx.x * 256 + threadIdx.x;
  o[idx] = f2bf(x[idx]);
}

// ---------------- LayerNorm: fp32 x -> bf16 out ----------------
__global__ __launch_bounds__(256) void ln_kernel(const float* __restrict__ x,
                                                 const float* __restrict__ g,
                                                 const float* __restrict__ bta,
                                                 u16* __restrict__ out){
  int wave = threadIdx.x >> 6, lane = threadIdx.x & 63;
  size_t row = (size_t)blockIdx.x * 4 + wave;
  const float* xr = x + row * 512 + lane * 8;
  f32x4 v0 = *(const f32x4*)xr;
  f32x4 v1 = *(const f32x4*)(xr + 4);
  float s  = v0[0]+v0[1]+v0[2]+v0[3] + v1[0]+v1[1]+v1[2]+v1[3];
  float s2 = v0[0]*v0[0]+v0[1]*v0[1]+v0[2]*v0[2]+v0[3]*v0[3]
           + v1[0]*v1[0]+v1[1]*v1[1]+v1[2]*v1[2]+v1[3]*v1[3];
  #pragma unroll
  for (int off = 1; off < 64; off <<= 1){
    s  += __shfl_xor(s, off);
    s2 += __shfl_xor(s2, off);
  }
  float mean = s * (1.0f / 512.0f);
  float var  = s2 * (1.0f / 512.0f) - mean * mean;
  float rstd = rsqrtf(var + 1e-5f);
  int c = lane * 8;
  u16x8 o;
  #pragma unroll
  for (int j = 0; j < 8; j++){
    float xv = (j < 4) ? v0[j] : v1[j - 4];
    o[j] = f2bf((xv - mean) * rstd * g[c + j] + bta[c + j]);
  }
  *(u16x8*)(out + row * 512 + c) = o;
}

// ---------------- GEMM: out[M,N] = A[M,K](bf16) @ W[N,K]^T + bias(fp32) ----------------
#define EPI_BF16 0
#define EPI_GELU 1
#define EPI_F32  2
#define EPI_RES  3

template<int EPI>
__global__ __launch_bounds__(256) void gemm_bt(const u16* __restrict__ A, int lda,
                                               const u16* __restrict__ W, int ldw,
                                               const float* __restrict__ bias,
                                               u16* __restrict__ outb, float* __restrict__ outf,
                                               int ldo, int N, int K){
  int wave = threadIdx.x >> 6, lane = threadIdx.x & 63;
  int l15 = lane & 15, quad = lane >> 4;
  int tm = blockIdx.x * 64 + wave * 16;
  int tn = blockIdx.y * 64;
  const u16* Ap = A + (size_t)(tm + l15) * lda + quad * 8;
  const u16* Wp0; const u16* Wp1; const u16* Wp2; const u16* Wp3;
  {
    int c0 = tn + 0*16 + l15;  int c1 = tn + 1*16 + l15;
    int c2 = tn + 2*16 + l15;  int c3 = tn + 3*16 + l15;
    Wp0 = W + (size_t)(c0 < N ? c0 : N - 1) * ldw + quad * 8;
    Wp1 = W + (size_t)(c1 < N ? c1 : N - 1) * ldw + quad * 8;
    Wp2 = W + (size_t)(c2 < N ? c2 : N - 1) * ldw + quad * 8;
    Wp3 = W + (size_t)(c3 < N ? c3 : N - 1) * ldw + quad * 8;
  }
  f32x4 acc0 = {0,0,0,0}, acc1 = {0,0,0,0}, acc2 = {0,0,0,0}, acc3 = {0,0,0,0};
  for (int k = 0; k < K; k += 32){
    s16x8 a  = *(const s16x8*)(Ap + k);
    s16x8 b0 = *(const s16x8*)(Wp0 + k);
    s16x8 b1 = *(const s16x8*)(Wp1 + k);
    s16x8 b2 = *(const s16x8*)(Wp2 + k);
    s16x8 b3 = *(const s16x8*)(Wp3 + k);
    acc0 = __builtin_amdgcn_mfma_f32_16x16x32_bf16(a, b0, acc0, 0, 0, 0);
    acc1 = __builtin_amdgcn_mfma_f32_16x16x32_bf16(a, b1, acc1, 0, 0, 0);
    acc2 = __builtin_amdgcn_mfma_f32_16x16x32_bf16(a, b2, acc2, 0, 0, 0);
    acc3 = __builtin_amdgcn_mfma_f32_16x16x32_bf16(a, b3, acc3, 0, 0, 0);
  }
  f32x4 accs[4] = {acc0, acc1, acc2, acc3};
  #pragma unroll
  for (int j = 0; j < 4; j++){
    int col = tn + j * 16 + l15;
    if (col >= N) continue;
    float bv = bias ? bias[col] : 0.0f;
    #pragma unroll
    for (int r = 0; r < 4; r++){
      int row = tm + quad * 4 + r;
      float v = accs[j][r] + bv;
      size_t idx = (size_t)row * ldo + col;
      if (EPI == EPI_BF16){
        outb[idx] = f2bf(v);
      } else if (EPI == EPI_GELU){
        float gv = 0.5f * v * (1.0f + erff(v * 0.7071067811865475f));
        outb[idx] = f2bf(gv);
      } else if (EPI == EPI_F32){
        outf[idx] = v;
      } else {
        outf[idx] += v;
      }
    }
  }
}

// ---------------- flash attention (vector ALU), full (no mask) ----------------
// grid: (T/32, B*NH); block 256. q-tile 32, k-tile 64, dh=64.
__global__ __launch_bounds__(256) void attn_kernel(const u16* __restrict__ Qp, int qstride,
                                                   const u16* __restrict__ Kp,
                                                   const u16* __restrict__ Vp, int kvstride,
                                                   u16* __restrict__ Op){
  __shared__ float Qs[32][68];   // [q][d], pre-scaled by 1/8
  __shared__ float Kt[64][68];   // [d][k]
  __shared__ float Vs[64][68];   // [k][d]
  __shared__ float Ps[32][68];   // [q][k]
  int bh = blockIdx.y;
  int b = bh >> 3, h = bh & 7;
  int q0 = blockIdx.x * 32;
  int tid = threadIdx.x;
  const u16* Qb = Qp + (size_t)(b * 512 + q0) * qstride + h * 64;
  const u16* Kb = Kp + (size_t)(b * 512) * kvstride + h * 64;
  const u16* Vb = Vp + (size_t)(b * 512) * kvstride + h * 64;
  for (int i = tid; i < 32 * 64; i += 256){
    int r = i >> 6, c = i & 63;
    Qs[r][c] = bf2f(Qb[(size_t)r * qstride + c]) * 0.125f;
  }
  int tr = tid >> 4, tc = tid & 15;      // q rows 2tr,2tr+1 ; cols 4tc..4tc+3
  float m0 = -1e30f, m1 = -1e30f, l0 = 0.0f, l1 = 0.0f;
  f32x4 O0 = {0,0,0,0}, O1 = {0,0,0,0};
  for (int kt = 0; kt < 512; kt += 64){
    __syncthreads();
    for (int i = tid; i < 64 * 64; i += 256){
      int r = i >> 6, c = i & 63;
      Kt[c][r] = bf2f(Kb[(size_t)(kt + r) * kvstride + c]);
      Vs[r][c] = bf2f(Vb[(size_t)(kt + r) * kvstride + c]);
    }
    __syncthreads();
    f32x4 s0 = {0,0,0,0}, s1 = {0,0,0,0};
    #pragma unroll 8
    for (int d = 0; d < 64; d++){
      f32x4 kk = *(const f32x4*)&Kt[d][tc * 4];
      float qv0 = Qs[2 * tr][d];
      float qv1 = Qs[2 * tr + 1][d];
      s0 += qv0 * kk;
      s1 += qv1 * kk;
    }
    float rm0 = fmaxf(fmaxf(s0[0], s0[1]), fmaxf(s0[2], s0[3]));
    float rm1 = fmaxf(fmaxf(s1[0], s1[1]), fmaxf(s1[2], s1[3]));
    #pragma unroll
    for (int off = 1; off < 16; off <<= 1){
      rm0 = fmaxf(rm0, __shfl_xor(rm0, off));
      rm1 = fmaxf(rm1, __shfl_xor(rm1, off));
    }
    float mn0 = fmaxf(m0, rm0), mn1 = fmaxf(m1, rm1);
    float a0 = __expf(m0 - mn0), a1 = __expf(m1 - mn1);
    m0 = mn0; m1 = mn1;
    f32x4 p0, p1;
    float rs0 = 0.0f, rs1 = 0.0f;
    #pragma unroll
    for (int j = 0; j < 4; j++){
      p0[j] = __expf(s0[j] - mn0); rs0 += p0[j];
      p1[j] = __expf(s1[j] - mn1); rs1 += p1[j];
    }
    #pragma unroll
    for (int off = 1; off < 16; off <<= 1){
      rs0 += __shfl_xor(rs0, off);
      rs1 += __shfl_xor(rs1, off);
    }
    l0 = l0 * a0 + rs0;
    l1 = l1 * a1 + rs1;
    *(f32x4*)&Ps[2 * tr][tc * 4] = p0;
    *(f32x4*)&Ps[2 * tr + 1][tc * 4] = p1;
    O0 *= a0; O1 *= a1;
    __syncthreads();
    #pragma unroll 4
    for (int k2 = 0; k2 < 64; k2 += 4){
      f32x4 pa = *(const f32x4*)&Ps[2 * tr][k2];
      f32x4 pb = *(const f32x4*)&Ps[2 * tr + 1][k2];
      f32x4 va = *(const f32x4*)&Vs[k2][tc * 4];
      f32x4 vb = *(const f32x4*)&Vs[k2 + 1][tc * 4];
      f32x4 vc = *(const f32x4*)&Vs[k2 + 2][tc * 4];
      f32x4 vd = *(const f32x4*)&Vs[k2 + 3][tc * 4];
      O0 += pa[0]*va + pa[1]*vb + pa[2]*vc + pa[3]*vd;
      O1 += pb[0]*va + pb[1]*vb + pb[2]*vc + pb[3]*vd;
    }
  }
  float i0 = 1.0f / l0, i1 = 1.0f / l1;
  u16* ob0 = Op + (size_t)(b * 512 + q0 + 2 * tr) * 512 + h * 64 + tc * 4;
  u16* ob1 = ob0 + 512;
  #pragma unroll
  for (int j = 0; j < 4; j++){
    ob0[j] = f2bf(O0[j] * i0);
    ob1[j] = f2bf(O1[j] * i1);
  }
}

// ---------------- forward-kinematics tail (fp32 out) ----------------
__global__ __launch_bounds__(256) void fk_kernel(const float* __restrict__ head, float* __restrict__ out){
  const int P[50] = {-1,0,1,2,3,1,5,6,1,
    4,9,10,11, 4,13,14,15, 4,17,18,19, 4,21,22,23, 4,25,26,27,
    7,29,30,31, 7,33,34,35, 7,37,38,39, 7,41,42,43, 7,45,46,47,
    8};
  int r = blockIdx.x * 256 + threadIdx.x;        // 16384 rows
  const float* o = head + (size_t)r * 102;
  float* ob = out + (size_t)r * 150;
  float g[50], px[50], py[50];
  g[0] = 0.0f; px[0] = o[100]; py[0] = o[101];
  ob[0] = px[0]; ob[1] = py[0]; ob[2] = 1.0f;
  #pragma unroll
  for (int j = 1; j < 50; j++){
    int p = P[j];
    float gc = g[p] + o[j];
    g[j] = gc;
    float sc = o[50 + j];
    float sn = sinf(gc), cs = cosf(gc);
    px[j] = px[p] + cs * sc;
    py[j] = py[p] + sn * sc;
    ob[3 * j] = px[j]; ob[3 * j + 1] = py[j]; ob[3 * j + 2] = 1.0f;
  }
}

extern "C" void kernel_launch(void* const* d_in, const int* in_sizes, int n_in,
                              void* d_out, int out_size, void* d_ws, size_t ws_size,
                              hipStream_t stream){
  (void)in_sizes; (void)n_in; (void)out_size; (void)ws_size;
  const float* memory   = (const float*)d_in[0];
  const float* in_w     = (const float*)d_in[1];
  const float* in_b     = (const float*)d_in[2];
  const float* conv_w   = (const float*)d_in[3];
  const float* conv_b   = (const float*)d_in[4];
  const float* qemb     = (const float*)d_in[5];
  const float* sa_in_w  = (const float*)d_in[6];
  const float* sa_in_b  = (const float*)d_in[7];
  const float* sa_out_w = (const float*)d_in[8];
  const float* sa_out_b = (const float*)d_in[9];
  const float* ca_in_w  = (const float*)d_in[10];
  const float* ca_in_b  = (const float*)d_in[11];
  const float* ca_out_w = (const float*)d_in[12];
  const float* ca_out_b = (const float*)d_in[13];
  const float* ln1_g    = (const float*)d_in[14];
  const float* ln1_b    = (const float*)d_in[15];
  const float* ln2_g    = (const float*)d_in[16];
  const float* ln2_b    = (const float*)d_in[17];
  const float* ln3_g    = (const float*)d_in[18];
  const float* ln3_b    = (const float*)d_in[19];
  const float* ff1_w    = (const float*)d_in[20];
  const float* ff1_b    = (const float*)d_in[21];
  const float* ff2_w    = (const float*)d_in[22];
  const float* ff2_b    = (const float*)d_in[23];
  const float* out_w    = (const float*)d_in[24];
  const float* out_b    = (const float*)d_in[25];

  char* ws = (char*)d_ws;
  float* pe    = (float*)(ws);                    //  1,048,576 B
  float* x     = (float*)(ws + 1048576);          // 33,554,432 B (fp32 residual)
  u16*   memb  = (u16*)  (ws + 34603008);         // 16,777,216 B
  u16*   hb    = (u16*)  (ws + 51380224);         // 16,777,216 B (LN out / attn out)
  u16*   wp    = (u16*)  (ws + 68157440);         // 36,280,320 B bf16 weight pool
  char*  big   =          ws + 104857600;         // 50,331,648 B phase-shared (end 155,189,248)

  // weight pool offsets (elements)
  u16* w_in    = wp + 0;          // 262,144
  u16* w_convt = wp + 262144;     // 1,048,576
  u16* w_sain  = wp + 1310720;    // 3,145,728
  u16* w_saout = wp + 4456448;    // 1,048,576
  u16* w_cain  = wp + 5505024;    // 3,145,728
  u16* w_caout = wp + 8650752;    // 1,048,576
  u16* w_ff1   = wp + 9699328;    // 4,194,304
  u16* w_ff2   = wp + 13893632;   // 4,194,304
  u16* w_out   = wp + 18087936;   // 52,224

  // big-region phase views
  u16* mcast   = (u16*)big;                       // 4096x512 bf16 (conv phase)
  u16* mb      = (u16*)(big + 4194304);           // 4096x512
  u16* convlin = (u16*)(big + 8388608);           // 4096x2048
  u16* qkv = (u16*)big;                           // 16384x1536 (SA phase)
  u16* qb  = (u16*)big;                           // 16384x512  (CA phase)
  u16* kvb = (u16*)(big + 16777216);              // 16384x1024 (CA phase)
  u16* f1b = (u16*)big;                           // 8192x2048  (FF phase, half rows)
  float* head = (float*)big;                      // 16384x102 fp32 (head phase)

  dim3 blk(256);
  // ---- prologue: casts + pe ----
  pe_kernel<<<1024, blk, 0, stream>>>(pe);
  castf2b_v4<<<2048,  blk, 0, stream>>>(memory,   mcast,   524288);
  castf2b_v4<<<256,   blk, 0, stream>>>(in_w,     w_in,    65536);
  convw_t_kernel<<<4096, blk, 0, stream>>>(conv_w, w_convt);
  castf2b_v4<<<3072,  blk, 0, stream>>>(sa_in_w,  w_sain,  786432);
  castf2b_v4<<<1024,  blk, 0, stream>>>(sa_out_w, w_saout, 262144);
  castf2b_v4<<<3072,  blk, 0, stream>>>(ca_in_w,  w_cain,  786432);
  castf2b_v4<<<1024,  blk, 0, stream>>>(ca_out_w, w_caout, 262144);
  castf2b_v4<<<4096,  blk, 0, stream>>>(ff1_w,    w_ff1,   1048576);
  castf2b_v4<<<4096,  blk, 0, stream>>>(ff2_w,    w_ff2,   1048576);
  castf2b_v4<<<51,    blk, 0, stream>>>(out_w,    w_out,   13056);
  initx_kernel<<<32768, blk, 0, stream>>>(qemb, pe, x);
  // m = memory @ in_proj_w^T + b     (4096 x 512)
  gemm_bt<EPI_BF16><<<dim3(64, 8),  blk, 0, stream>>>(mcast, 512, w_in, 512, in_b, mb, nullptr, 512, 512, 512);
  // convlin = m @ convwt^T           (4096 x 2048)
  gemm_bt<EPI_BF16><<<dim3(64, 32), blk, 0, stream>>>(mb, 512, w_convt, 512, nullptr, convlin, nullptr, 2048, 2048, 512);
  mem_kernel<<<32768, blk, 0, stream>>>(convlin, conv_b, pe, memb);

  for (int l = 0; l < 4; l++){
    // ---- self attention ----
    ln_kernel<<<4096, blk, 0, stream>>>(x, ln1_g + l*512, ln1_b + l*512, hb);
    gemm_bt<EPI_BF16><<<dim3(256, 24), blk, 0, stream>>>(hb, 512, w_sain + (size_t)l*786432, 512,
                                                         sa_in_b + l*1536, qkv, nullptr, 1536, 1536, 512);
    attn_kernel<<<dim3(16, 256), blk, 0, stream>>>(qkv, 1536, qkv + 512, qkv + 1024, 1536, hb);
    gemm_bt<EPI_RES><<<dim3(256, 8), blk, 0, stream>>>(hb, 512, w_saout + (size_t)l*262144, 512,
                                                       sa_out_b + l*512, nullptr, x, 512, 512, 512);
    // ---- cross attention ----
    ln_kernel<<<4096, blk, 0, stream>>>(x, ln2_g + l*512, ln2_b + l*512, hb);
    gemm_bt<EPI_BF16><<<dim3(256, 8),  blk, 0, stream>>>(hb, 512, w_cain + (size_t)l*786432, 512,
                                                         ca_in_b + l*1536, qb, nullptr, 512, 512, 512);
    gemm_bt<EPI_BF16><<<dim3(256, 16), blk, 0, stream>>>(memb, 512, w_cain + (size_t)l*786432 + 262144, 512,
                                                         ca_in_b + l*1536 + 512, kvb, nullptr, 1024, 1024, 512);
    attn_kernel<<<dim3(16, 256), blk, 0, stream>>>(qb, 512, kvb, kvb + 512, 1024, hb);
    gemm_bt<EPI_RES><<<dim3(256, 8), blk, 0, stream>>>(hb, 512, w_caout + (size_t)l*262144, 512,
                                                       ca_out_b + l*512, nullptr, x, 512, 512, 512);
    // ---- feed forward (two row-halves to bound scratch) ----
    ln_kernel<<<4096, blk, 0, stream>>>(x, ln3_g + l*512, ln3_b + l*512, hb);
    for (int h2 = 0; h2 < 2; h2++){
      size_t ro = (size_t)h2 * 8192;
      gemm_bt<EPI_GELU><<<dim3(128, 32), blk, 0, stream>>>(hb + ro*512, 512, w_ff1 + (size_t)l*1048576, 512,
                                                           ff1_b + l*2048, f1b, nullptr, 2048, 2048, 512);
      gemm_bt<EPI_RES><<<dim3(128, 8), blk, 0, stream>>>(f1b, 2048, w_ff2 + (size_t)l*1048576, 2048,
                                                         ff2_b + l*512, nullptr, x + ro*512, 512, 512, 2048);
    }
  }
  cast_kernel<<<32768, blk, 0, stream>>>(x, hb);
  gemm_bt<EPI_F32><<<dim3(256, 2), blk, 0, stream>>>(hb, 512, w_out, 512, out_b, nullptr, head, 102, 102, 512);
  fk_kernel<<<64, blk, 0, stream>>>(head, (float*)d_out);
}

// Round 3
// 5695.044 us; speedup vs baseline: 1.4646x; 1.4646x over previous
//
#include <hip/hip_runtime.h>
#include <cstdint>

typedef unsigned short u16;
typedef short s16x8 __attribute__((ext_vector_type(8)));
typedef u16   u16x4 __attribute__((ext_vector_type(4)));
typedef u16   u16x8 __attribute__((ext_vector_type(8)));
typedef float f32x4 __attribute__((ext_vector_type(4)));

__device__ __forceinline__ float bf2f(u16 u){
  union { unsigned int i; float f; } v; v.i = ((unsigned int)u) << 16; return v.f;
}
__device__ __forceinline__ u16 f2bf(float f){
  union { float f; unsigned int i; } v; v.f = f;
  unsigned int r = v.i + 0x7fffu + ((v.i >> 16) & 1u);
  return (u16)(r >> 16);
}

// ---------------- fp32 -> bf16 cast (vectorized), n multiple of 4 ----------------
__global__ __launch_bounds__(256) void castf2b_v4(const float* __restrict__ src,
                                                  u16* __restrict__ dst, int n4){
  int i = blockIdx.x * 256 + threadIdx.x;
  if (i >= n4) return;
  f32x4 v = *(const f32x4*)(src + i * 4);
  u16x4 o;
  o[0] = f2bf(v[0]); o[1] = f2bf(v[1]); o[2] = f2bf(v[2]); o[3] = f2bf(v[3]);
  *(u16x4*)(dst + i * 4) = o;
}

// ---------------- positional encoding (fp32) ----------------
__global__ __launch_bounds__(256) void pe_kernel(float* __restrict__ pe){
  int idx = blockIdx.x * 256 + threadIdx.x;       // 512*512
  int t = idx >> 9, h = idx & 511;
  int i2 = h >> 1;
  float freq = expf((float)(2 * i2) * (-9.210340371976184f / 512.0f));
  float a = (float)t * freq;
  pe[idx] = (h & 1) ? cosf(a) : sinf(a);
}

// ---------------- transpose+cast conv_w (C,D,K) fp32 -> (K*D, C) bf16 ----------------
__global__ __launch_bounds__(256) void convw_t_kernel(const float* __restrict__ w, u16* __restrict__ wt){
  int idx = blockIdx.x * 256 + threadIdx.x;       // 2048*512, idx = n*512 + c
  int n = idx >> 9, c = idx & 511;                // n = k*512 + d
  int k = n >> 9, d = n & 511;
  wt[idx] = f2bf(w[c * 2048 + d * 4 + k]);
}

// ---------------- x = query_emb + pe (fp32 residual stream) ----------------
__global__ __launch_bounds__(256) void initx_kernel(const float* __restrict__ qe,
                                                    const float* __restrict__ pe,
                                                    float* __restrict__ x){
  int idx = blockIdx.x * 256 + threadIdx.x;       // 32*512*512
  int th = idx & (512 * 512 - 1);
  x[idx] = qe[th] + pe[th];
}

// ---------------- mem[b, s*4+k, d] = convlin[b*128+s, k*512+d] + conv_b[d] + pe ----------------
__global__ __launch_bounds__(256) void mem_kernel(const u16* __restrict__ lin,
                                                  const float* __restrict__ cb,
                                                  const float* __restrict__ pe,
                                                  u16* __restrict__ mem){
  int idx = blockIdx.x * 256 + threadIdx.x;       // 32*512*512
  int d = idx & 511;
  int t = (idx >> 9) & 511;
  int b = idx >> 18;
  int s = t >> 2, k = t & 3;
  float v = bf2f(lin[(size_t)(b * 128 + s) * 2048 + k * 512 + d]) + cb[d] + pe[t * 512 + d];
  mem[idx] = f2bf(v);
}

// ---------------- cast fp32 -> bf16 ----------------
__global__ __launch_bounds__(256) void cast_kernel(const float* __restrict__ x, u16* __restrict__ o){
  int idx = blockIdx.x * 256 + threadIdx.x;
  o[idx] = f2bf(x[idx]);
}

// ---------------- LayerNorm: fp32 x -> bf16 out ----------------
__global__ __launch_bounds__(256) void ln_kernel(const float* __restrict__ x,
                                                 const float* __restrict__ g,
                                                 const float* __restrict__ bta,
                                                 u16* __restrict__ out){
  int wave = threadIdx.x >> 6, lane = threadIdx.x & 63;
  size_t row = (size_t)blockIdx.x * 4 + wave;
  const float* xr = x + row * 512 + lane * 8;
  f32x4 v0 = *(const f32x4*)xr;
  f32x4 v1 = *(const f32x4*)(xr + 4);
  float s  = v0[0]+v0[1]+v0[2]+v0[3] + v1[0]+v1[1]+v1[2]+v1[3];
  float s2 = v0[0]*v0[0]+v0[1]*v0[1]+v0[2]*v0[2]+v0[3]*v0[3]
           + v1[0]*v1[0]+v1[1]*v1[1]+v1[2]*v1[2]+v1[3]*v1[3];
  #pragma unroll
  for (int off = 1; off < 64; off <<= 1){
    s  += __shfl_xor(s, off);
    s2 += __shfl_xor(s2, off);
  }
  float mean = s * (1.0f / 512.0f);
  float var  = s2 * (1.0f / 512.0f) - mean * mean;
  float rstd = rsqrtf(var + 1e-5f);
  int c = lane * 8;
  u16x8 o;
  #pragma unroll
  for (int j = 0; j < 8; j++){
    float xv = (j < 4) ? v0[j] : v1[j - 4];
    o[j] = f2bf((xv - mean) * rstd * g[c + j] + bta[c + j]);
  }
  *(u16x8*)(out + row * 512 + c) = o;
}

// ---------------- GEMM: out[M,N] = A[M,K](bf16) @ W[N,K]^T + bias(fp32) ----------------
#define EPI_BF16 0
#define EPI_GELU 1
#define EPI_F32  2
#define EPI_RES  3

template<int EPI>
__global__ __launch_bounds__(256) void gemm_bt(const u16* __restrict__ A, int lda,
                                               const u16* __restrict__ W, int ldw,
                                               const float* __restrict__ bias,
                                               u16* __restrict__ outb, float* __restrict__ outf,
                                               int ldo, int N, int K){
  int wave = threadIdx.x >> 6, lane = threadIdx.x & 63;
  int l15 = lane & 15, quad = lane >> 4;
  int tm = blockIdx.x * 64 + wave * 16;
  int tn = blockIdx.y * 64;
  const u16* Ap = A + (size_t)(tm + l15) * lda + quad * 8;
  const u16* Wp0; const u16* Wp1; const u16* Wp2; const u16* Wp3;
  {
    int c0 = tn + 0*16 + l15;  int c1 = tn + 1*16 + l15;
    int c2 = tn + 2*16 + l15;  int c3 = tn + 3*16 + l15;
    Wp0 = W + (size_t)(c0 < N ? c0 : N - 1) * ldw + quad * 8;
    Wp1 = W + (size_t)(c1 < N ? c1 : N - 1) * ldw + quad * 8;
    Wp2 = W + (size_t)(c2 < N ? c2 : N - 1) * ldw + quad * 8;
    Wp3 = W + (size_t)(c3 < N ? c3 : N - 1) * ldw + quad * 8;
  }
  f32x4 acc0 = {0,0,0,0}, acc1 = {0,0,0,0}, acc2 = {0,0,0,0}, acc3 = {0,0,0,0};
  for (int k = 0; k < K; k += 32){
    s16x8 a  = *(const s16x8*)(Ap + k);
    s16x8 b0 = *(const s16x8*)(Wp0 + k);
    s16x8 b1 = *(const s16x8*)(Wp1 + k);
    s16x8 b2 = *(const s16x8*)(Wp2 + k);
    s16x8 b3 = *(const s16x8*)(Wp3 + k);
    acc0 = __builtin_amdgcn_mfma_f32_16x16x32_bf16(a, b0, acc0, 0, 0, 0);
    acc1 = __builtin_amdgcn_mfma_f32_16x16x32_bf16(a, b1, acc1, 0, 0, 0);
    acc2 = __builtin_amdgcn_mfma_f32_16x16x32_bf16(a, b2, acc2, 0, 0, 0);
    acc3 = __builtin_amdgcn_mfma_f32_16x16x32_bf16(a, b3, acc3, 0, 0, 0);
  }
  f32x4 accs[4] = {acc0, acc1, acc2, acc3};
  #pragma unroll
  for (int j = 0; j < 4; j++){
    int col = tn + j * 16 + l15;
    if (col >= N) continue;
    float bv = bias ? bias[col] : 0.0f;
    #pragma unroll
    for (int r = 0; r < 4; r++){
      int row = tm + quad * 4 + r;
      float v = accs[j][r] + bv;
      size_t idx = (size_t)row * ldo + col;
      if (EPI == EPI_BF16){
        outb[idx] = f2bf(v);
      } else if (EPI == EPI_GELU){
        float gv = 0.5f * v * (1.0f + erff(v * 0.7071067811865475f));
        outb[idx] = f2bf(gv);
      } else if (EPI == EPI_F32){
        outf[idx] = v;
      } else {
        outf[idx] += v;
      }
    }
  }
}

// ---------------- MFMA flash attention ----------------
// grid (T/64=8, B*NH=256); block 256 (4 waves, 16 q-rows each). kv len 512, dh=64.
// Layouts (verified 16x16x32 bf16): A m=lane&15,k=quad*8+j ; B k=quad*8+j,n=lane&15 ;
// C/D col=lane&15,row=quad*4+reg.
__global__ __launch_bounds__(256) void attn_mfma(const u16* __restrict__ Qp, int qstride,
                                                 const u16* __restrict__ Kp,
                                                 const u16* __restrict__ Vp, int kvstride,
                                                 u16* __restrict__ Op){
  __shared__ __align__(16) u16 Ks[64][72];     // [kv][d]
  __shared__ __align__(16) u16 Vt[64][72];     // [d][kv], kv-blocks XOR-swizzled by (d>>3)&7
  __shared__ __align__(16) u16 Ps[4][16][72];  // per-wave P  [q][kv]
  int bh = blockIdx.y;
  int b = bh >> 3, h = bh & 7;
  int q0 = blockIdx.x * 64;
  int tid = threadIdx.x;
  int wv = tid >> 6, lane = tid & 63, l15 = lane & 15, quad = lane >> 4;
  const u16* Qb = Qp + (size_t)(b * 512 + q0 + wv * 16) * qstride + h * 64;
  const u16* Kb = Kp + (size_t)(b * 512) * kvstride + h * 64;
  const u16* Vb = Vp + (size_t)(b * 512) * kvstride + h * 64;
  // Q fragments (held in registers across all kv tiles)
  s16x8 qa0 = *(const s16x8*)(Qb + (size_t)l15 * qstride + quad * 8);
  s16x8 qa1 = *(const s16x8*)(Qb + (size_t)l15 * qstride + 32 + quad * 8);

  f32x4 o0 = {0,0,0,0}, o1 = {0,0,0,0}, o2 = {0,0,0,0}, o3 = {0,0,0,0};
  f32x4 m = {-3e38f, -3e38f, -3e38f, -3e38f};
  f32x4 l = {0,0,0,0};

  for (int kt = 0; kt < 512; kt += 64){
    __syncthreads();
    // stage K (natural) and V (transposed+swizzled)
    for (int i = tid; i < 512; i += 256){
      int r = i >> 3, c8 = i & 7;
      u16x8 kv8 = *(const u16x8*)(Kb + (size_t)(kt + r) * kvstride + c8 * 8);
      *(u16x8*)(&Ks[r][c8 * 8]) = kv8;
      u16x8 vv8 = *(const u16x8*)(Vb + (size_t)(kt + r) * kvstride + c8 * 8);
      int col = (((r >> 3) ^ c8) << 3) + (r & 7);
      #pragma unroll
      for (int j = 0; j < 8; j++) Vt[c8 * 8 + j][col] = vv8[j];
    }
    __syncthreads();
    // ---- S = (Q K^T) * 1/8, 4 tiles of 16 kv each ----
    f32x4 st[4];
    #pragma unroll
    for (int t = 0; t < 4; t++){
      s16x8 kb0 = *(const s16x8*)(&Ks[t * 16 + l15][quad * 8]);
      s16x8 kb1 = *(const s16x8*)(&Ks[t * 16 + l15][32 + quad * 8]);
      f32x4 acc = {0,0,0,0};
      acc = __builtin_amdgcn_mfma_f32_16x16x32_bf16(qa0, kb0, acc, 0, 0, 0);
      acc = __builtin_amdgcn_mfma_f32_16x16x32_bf16(qa1, kb1, acc, 0, 0, 0);
      st[t] = acc * 0.125f;
    }
    // ---- online softmax (rows = quad*4+r, cols = t*16+l15) ----
    f32x4 rowm;
    #pragma unroll
    for (int r = 0; r < 4; r++)
      rowm[r] = fmaxf(fmaxf(st[0][r], st[1][r]), fmaxf(st[2][r], st[3][r]));
    #pragma unroll
    for (int off = 1; off < 16; off <<= 1){
      #pragma unroll
      for (int r = 0; r < 4; r++) rowm[r] = fmaxf(rowm[r], __shfl_xor(rowm[r], off));
    }
    f32x4 alpha, rs = {0,0,0,0};
    float p[4][4];
    #pragma unroll
    for (int r = 0; r < 4; r++){
      float mn = fmaxf(m[r], rowm[r]);
      alpha[r] = __expf(m[r] - mn);
      m[r] = mn;
    }
    #pragma unroll
    for (int t = 0; t < 4; t++){
      #pragma unroll
      for (int r = 0; r < 4; r++){
        p[t][r] = __expf(st[t][r] - m[r]);
        rs[r] += p[t][r];
      }
    }
    #pragma unroll
    for (int off = 1; off < 16; off <<= 1){
      #pragma unroll
      for (int r = 0; r < 4; r++) rs[r] += __shfl_xor(rs[r], off);
    }
    #pragma unroll
    for (int r = 0; r < 4; r++) l[r] = l[r] * alpha[r] + rs[r];
    #pragma unroll
    for (int r = 0; r < 4; r++){
      o0[r] *= alpha[r]; o1[r] *= alpha[r]; o2[r] *= alpha[r]; o3[r] *= alpha[r];
    }
    // P -> LDS (C-layout scatter), then re-read as A-fragments
    #pragma unroll
    for (int t = 0; t < 4; t++){
      #pragma unroll
      for (int r = 0; r < 4; r++)
        Ps[wv][quad * 4 + r][t * 16 + l15] = f2bf(p[t][r]);
    }
    __syncthreads();
    s16x8 pa0 = *(const s16x8*)(&Ps[wv][l15][quad * 8]);
    s16x8 pa1 = *(const s16x8*)(&Ps[wv][l15][32 + quad * 8]);
    // ---- O += P V, 4 d-tiles ----
    #pragma unroll
    for (int u = 0; u < 4; u++){
      int d0 = u * 16 + l15;
      int sw = (d0 >> 3) & 7;
      s16x8 vb0 = *(const s16x8*)(&Vt[d0][(quad ^ sw) << 3]);
      s16x8 vb1 = *(const s16x8*)(&Vt[d0][((quad + 4) ^ sw) << 3]);
      f32x4* ou = (u == 0) ? &o0 : (u == 1) ? &o1 : (u == 2) ? &o2 : &o3;
      *ou = __builtin_amdgcn_mfma_f32_16x16x32_bf16(pa0, vb0, *ou, 0, 0, 0);
      *ou = __builtin_amdgcn_mfma_f32_16x16x32_bf16(pa1, vb1, *ou, 0, 0, 0);
    }
  }
  // epilogue
  f32x4 inv;
  #pragma unroll
  for (int r = 0; r < 4; r++) inv[r] = 1.0f / l[r];
  u16* ob = Op + (size_t)(b * 512 + q0 + wv * 16 + quad * 4) * 512 + h * 64 + l15;
  #pragma unroll
  for (int r = 0; r < 4; r++){
    ob[(size_t)r * 512 +  0] = f2bf(o0[r] * inv[r]);
    ob[(size_t)r * 512 + 16] = f2bf(o1[r] * inv[r]);
    ob[(size_t)r * 512 + 32] = f2bf(o2[r] * inv[r]);
    ob[(size_t)r * 512 + 48] = f2bf(o3[r] * inv[r]);
  }
}

// ---------------- forward-kinematics tail (fp32 out) ----------------
__global__ __launch_bounds__(256) void fk_kernel(const float* __restrict__ head, float* __restrict__ out){
  const int P[50] = {-1,0,1,2,3,1,5,6,1,
    4,9,10,11, 4,13,14,15, 4,17,18,19, 4,21,22,23, 4,25,26,27,
    7,29,30,31, 7,33,34,35, 7,37,38,39, 7,41,42,43, 7,45,46,47,
    8};
  int r = blockIdx.x * 256 + threadIdx.x;        // 16384 rows
  const float* o = head + (size_t)r * 102;
  float* ob = out + (size_t)r * 150;
  float g[50], px[50], py[50];
  g[0] = 0.0f; px[0] = o[100]; py[0] = o[101];
  ob[0] = px[0]; ob[1] = py[0]; ob[2] = 1.0f;
  #pragma unroll
  for (int j = 1; j < 50; j++){
    int p = P[j];
    float gc = g[p] + o[j];
    g[j] = gc;
    float sc = o[50 + j];
    float sn = sinf(gc), cs = cosf(gc);
    px[j] = px[p] + cs * sc;
    py[j] = py[p] + sn * sc;
    ob[3 * j] = px[j]; ob[3 * j + 1] = py[j]; ob[3 * j + 2] = 1.0f;
  }
}

extern "C" void kernel_launch(void* const* d_in, const int* in_sizes, int n_in,
                              void* d_out, int out_size, void* d_ws, size_t ws_size,
                              hipStream_t stream){
  (void)in_sizes; (void)n_in; (void)out_size; (void)ws_size;
  const float* memory   = (const float*)d_in[0];
  const float* in_w     = (const float*)d_in[1];
  const float* in_b     = (const float*)d_in[2];
  const float* conv_w   = (const float*)d_in[3];
  const float* conv_b   = (const float*)d_in[4];
  const float* qemb     = (const float*)d_in[5];
  const float* sa_in_w  = (const float*)d_in[6];
  const float* sa_in_b  = (const float*)d_in[7];
  const float* sa_out_w = (const float*)d_in[8];
  const float* sa_out_b = (const float*)d_in[9];
  const float* ca_in_w  = (const float*)d_in[10];
  const float* ca_in_b  = (const float*)d_in[11];
  const float* ca_out_w = (const float*)d_in[12];
  const float* ca_out_b = (const float*)d_in[13];
  const float* ln1_g    = (const float*)d_in[14];
  const float* ln1_b    = (const float*)d_in[15];
  const float* ln2_g    = (const float*)d_in[16];
  const float* ln2_b    = (const float*)d_in[17];
  const float* ln3_g    = (const float*)d_in[18];
  const float* ln3_b    = (const float*)d_in[19];
  const float* ff1_w    = (const float*)d_in[20];
  const float* ff1_b    = (const float*)d_in[21];
  const float* ff2_w    = (const float*)d_in[22];
  const float* ff2_b    = (const float*)d_in[23];
  const float* out_w    = (const float*)d_in[24];
  const float* out_b    = (const float*)d_in[25];

  char* ws = (char*)d_ws;
  float* pe    = (float*)(ws);                    //  1,048,576 B
  float* x     = (float*)(ws + 1048576);          // 33,554,432 B (fp32 residual)
  u16*   memb  = (u16*)  (ws + 34603008);         // 16,777,216 B
  u16*   hb    = (u16*)  (ws + 51380224);         // 16,777,216 B (LN out / attn out)
  u16*   wp    = (u16*)  (ws + 68157440);         // 36,280,320 B bf16 weight pool
  char*  big   =          ws + 104857600;         // 50,331,648 B phase-shared (end 155,189,248)

  // weight pool offsets (elements)
  u16* w_in    = wp + 0;          // 262,144
  u16* w_convt = wp + 262144;     // 1,048,576
  u16* w_sain  = wp + 1310720;    // 3,145,728
  u16* w_saout = wp + 4456448;    // 1,048,576
  u16* w_cain  = wp + 5505024;    // 3,145,728
  u16* w_caout = wp + 8650752;    // 1,048,576
  u16* w_ff1   = wp + 9699328;    // 4,194,304
  u16* w_ff2   = wp + 13893632;   // 4,194,304
  u16* w_out   = wp + 18087936;   // 52,224

  // big-region phase views
  u16* mcast   = (u16*)big;                       // 4096x512 bf16 (conv phase)
  u16* mb      = (u16*)(big + 4194304);           // 4096x512
  u16* convlin = (u16*)(big + 8388608);           // 4096x2048
  u16* qkv = (u16*)big;                           // 16384x1536 (SA phase)
  u16* qb  = (u16*)big;                           // 16384x512  (CA phase)
  u16* kvb = (u16*)(big + 16777216);              // 16384x1024 (CA phase)
  u16* f1b = (u16*)big;                           // 8192x2048  (FF phase, half rows)
  float* head = (float*)big;                      // 16384x102 fp32 (head phase)

  dim3 blk(256);
  // ---- prologue: casts + pe ----
  pe_kernel<<<1024, blk, 0, stream>>>(pe);
  castf2b_v4<<<2048,  blk, 0, stream>>>(memory,   mcast,   524288);
  castf2b_v4<<<256,   blk, 0, stream>>>(in_w,     w_in,    65536);
  convw_t_kernel<<<4096, blk, 0, stream>>>(conv_w, w_convt);
  castf2b_v4<<<3072,  blk, 0, stream>>>(sa_in_w,  w_sain,  786432);
  castf2b_v4<<<1024,  blk, 0, stream>>>(sa_out_w, w_saout, 262144);
  castf2b_v4<<<3072,  blk, 0, stream>>>(ca_in_w,  w_cain,  786432);
  castf2b_v4<<<1024,  blk, 0, stream>>>(ca_out_w, w_caout, 262144);
  castf2b_v4<<<4096,  blk, 0, stream>>>(ff1_w,    w_ff1,   1048576);
  castf2b_v4<<<4096,  blk, 0, stream>>>(ff2_w,    w_ff2,   1048576);
  castf2b_v4<<<51,    blk, 0, stream>>>(out_w,    w_out,   13056);
  initx_kernel<<<32768, blk, 0, stream>>>(qemb, pe, x);
  // m = memory @ in_proj_w^T + b     (4096 x 512)
  gemm_bt<EPI_BF16><<<dim3(64, 8),  blk, 0, stream>>>(mcast, 512, w_in, 512, in_b, mb, nullptr, 512, 512, 512);
  // convlin = m @ convwt^T           (4096 x 2048)
  gemm_bt<EPI_BF16><<<dim3(64, 32), blk, 0, stream>>>(mb, 512, w_convt, 512, nullptr, convlin, nullptr, 2048, 2048, 512);
  mem_kernel<<<32768, blk, 0, stream>>>(convlin, conv_b, pe, memb);

  for (int l = 0; l < 4; l++){
    // ---- self attention ----
    ln_kernel<<<4096, blk, 0, stream>>>(x, ln1_g + l*512, ln1_b + l*512, hb);
    gemm_bt<EPI_BF16><<<dim3(256, 24), blk, 0, stream>>>(hb, 512, w_sain + (size_t)l*786432, 512,
                                                         sa_in_b + l*1536, qkv, nullptr, 1536, 1536, 512);
    attn_mfma<<<dim3(8, 256), blk, 0, stream>>>(qkv, 1536, qkv + 512, qkv + 1024, 1536, hb);
    gemm_bt<EPI_RES><<<dim3(256, 8), blk, 0, stream>>>(hb, 512, w_saout + (size_t)l*262144, 512,
                                                       sa_out_b + l*512, nullptr, x, 512, 512, 512);
    // ---- cross attention ----
    ln_kernel<<<4096, blk, 0, stream>>>(x, ln2_g + l*512, ln2_b + l*512, hb);
    gemm_bt<EPI_BF16><<<dim3(256, 8),  blk, 0, stream>>>(hb, 512, w_cain + (size_t)l*786432, 512,
                                                         ca_in_b + l*1536, qb, nullptr, 512, 512, 512);
    gemm_bt<EPI_BF16><<<dim3(256, 16), blk, 0, stream>>>(memb, 512, w_cain + (size_t)l*786432 + 262144, 512,
                                                         ca_in_b + l*1536 + 512, kvb, nullptr, 1024, 1024, 512);
    attn_mfma<<<dim3(8, 256), blk, 0, stream>>>(qb, 512, kvb, kvb + 512, 1024, hb);
    gemm_bt<EPI_RES><<<dim3(256, 8), blk, 0, stream>>>(hb, 512, w_caout + (size_t)l*262144, 512,
                                                       ca_out_b + l*512, nullptr, x, 512, 512, 512);
    // ---- feed forward (two row-halves to bound scratch) ----
    ln_kernel<<<4096, blk, 0, stream>>>(x, ln3_g + l*512, ln3_b + l*512, hb);
    for (int h2 = 0; h2 < 2; h2++){
      size_t ro = (size_t)h2 * 8192;
      gemm_bt<EPI_GELU><<<dim3(128, 32), blk, 0, stream>>>(hb + ro*512, 512, w_ff1 + (size_t)l*1048576, 512,
                                                           ff1_b + l*2048, f1b, nullptr, 2048, 2048, 512);
      gemm_bt<EPI_RES><<<dim3(128, 8), blk, 0, stream>>>(f1b, 2048, w_ff2 + (size_t)l*1048576, 2048,
                                                         ff2_b + l*512, nullptr, x + ro*512, 512, 512, 2048);
    }
  }
  cast_kernel<<<32768, blk, 0, stream>>>(x, hb);
  gemm_bt<EPI_F32><<<dim3(256, 2), blk, 0, stream>>>(hb, 512, w_out, 512, out_b, nullptr, head, 102, 102, 512);
  fk_kernel<<<64, blk, 0, stream>>>(head, (float*)d_out);
}

// Round 5
// 2369.464 us; speedup vs baseline: 3.5202x; 2.4035x over previous
//
#include <hip/hip_runtime.h>
#include <cstdint>

typedef unsigned short u16;
typedef short s16x8 __attribute__((ext_vector_type(8)));
typedef u16   u16x4 __attribute__((ext_vector_type(4)));
typedef u16   u16x8 __attribute__((ext_vector_type(8)));
typedef float f32x4 __attribute__((ext_vector_type(4)));

__device__ __forceinline__ float bf2f(u16 u){
  union { unsigned int i; float f; } v; v.i = ((unsigned int)u) << 16; return v.f;
}
__device__ __forceinline__ u16 f2bf(float f){
  union { float f; unsigned int i; } v; v.f = f;
  unsigned int r = v.i + 0x7fffu + ((v.i >> 16) & 1u);
  return (u16)(r >> 16);
}

// async global->LDS, 16B per lane. LDS dst is wave-uniform base + lane*16.
__device__ __forceinline__ void gload16(const u16* g, u16* l, int lane){
#if __has_builtin(__builtin_amdgcn_global_load_lds)
  (void)lane;
  __builtin_amdgcn_global_load_lds((const __attribute__((address_space(1))) void*)g,
                                   (__attribute__((address_space(3))) void*)l, 16, 0, 0);
#else
  *(u16x8*)(l + lane * 8) = *(const u16x8*)g;
#endif
}

// ---------------- fp32 -> bf16 cast (vectorized), n multiple of 4 ----------------
__global__ __launch_bounds__(256) void castf2b_v4(const float* __restrict__ src,
                                                  u16* __restrict__ dst, int n4){
  int i = blockIdx.x * 256 + threadIdx.x;
  if (i >= n4) return;
  f32x4 v = *(const f32x4*)(src + i * 4);
  u16x4 o;
  o[0] = f2bf(v[0]); o[1] = f2bf(v[1]); o[2] = f2bf(v[2]); o[3] = f2bf(v[3]);
  *(u16x4*)(dst + i * 4) = o;
}

// ---------------- positional encoding (fp32) ----------------
__global__ __launch_bounds__(256) void pe_kernel(float* __restrict__ pe){
  int idx = blockIdx.x * 256 + threadIdx.x;       // 512*512
  int t = idx >> 9, h = idx & 511;
  int i2 = h >> 1;
  float freq = expf((float)(2 * i2) * (-9.210340371976184f / 512.0f));
  float a = (float)t * freq;
  pe[idx] = (h & 1) ? cosf(a) : sinf(a);
}

// ---------------- transpose+cast conv_w (C,D,K) fp32 -> (K*D, C) bf16 ----------------
__global__ __launch_bounds__(256) void convw_t_kernel(const float* __restrict__ w, u16* __restrict__ wt){
  int idx = blockIdx.x * 256 + threadIdx.x;       // 2048*512, idx = n*512 + c
  int n = idx >> 9, c = idx & 511;                // n = k*512 + d
  int k = n >> 9, d = n & 511;
  wt[idx] = f2bf(w[c * 2048 + d * 4 + k]);
}

// ---------------- x = query_emb + pe (fp32 residual stream) ----------------
__global__ __launch_bounds__(256) void initx_kernel(const float* __restrict__ qe,
                                                    const float* __restrict__ pe,
                                                    float* __restrict__ x){
  int idx = blockIdx.x * 256 + threadIdx.x;       // 32*512*512
  int th = idx & (512 * 512 - 1);
  x[idx] = qe[th] + pe[th];
}

// ---------------- mem[b, s*4+k, d] = convlin[b*128+s, k*512+d] + conv_b[d] + pe ----------------
__global__ __launch_bounds__(256) void mem_kernel(const u16* __restrict__ lin,
                                                  const float* __restrict__ cb,
                                                  const float* __restrict__ pe,
                                                  u16* __restrict__ mem){
  int idx = blockIdx.x * 256 + threadIdx.x;       // 32*512*512
  int d = idx & 511;
  int t = (idx >> 9) & 511;
  int b = idx >> 18;
  int s = t >> 2, k = t & 3;
  float v = bf2f(lin[(size_t)(b * 128 + s) * 2048 + k * 512 + d]) + cb[d] + pe[t * 512 + d];
  mem[idx] = f2bf(v);
}

// ---------------- cast fp32 -> bf16 ----------------
__global__ __launch_bounds__(256) void cast_kernel(const float* __restrict__ x, u16* __restrict__ o){
  int idx = blockIdx.x * 256 + threadIdx.x;
  o[idx] = f2bf(x[idx]);
}

// ---------------- LayerNorm: fp32 x -> bf16 out ----------------
__global__ __launch_bounds__(256) void ln_kernel(const float* __restrict__ x,
                                                 const float* __restrict__ g,
                                                 const float* __restrict__ bta,
                                                 u16* __restrict__ out){
  int wave = threadIdx.x >> 6, lane = threadIdx.x & 63;
  size_t row = (size_t)blockIdx.x * 4 + wave;
  const float* xr = x + row * 512 + lane * 8;
  f32x4 v0 = *(const f32x4*)xr;
  f32x4 v1 = *(const f32x4*)(xr + 4);
  float s  = v0[0]+v0[1]+v0[2]+v0[3] + v1[0]+v1[1]+v1[2]+v1[3];
  float s2 = v0[0]*v0[0]+v0[1]*v0[1]+v0[2]*v0[2]+v0[3]*v0[3]
           + v1[0]*v1[0]+v1[1]*v1[1]+v1[2]*v1[2]+v1[3]*v1[3];
  #pragma unroll
  for (int off = 1; off < 64; off <<= 1){
    s  += __shfl_xor(s, off);
    s2 += __shfl_xor(s2, off);
  }
  float mean = s * (1.0f / 512.0f);
  float var  = s2 * (1.0f / 512.0f) - mean * mean;
  float rstd = rsqrtf(var + 1e-5f);
  int c = lane * 8;
  u16x8 o;
  #pragma unroll
  for (int j = 0; j < 8; j++){
    float xv = (j < 4) ? v0[j] : v1[j - 4];
    o[j] = f2bf((xv - mean) * rstd * g[c + j] + bta[c + j]);
  }
  *(u16x8*)(out + row * 512 + c) = o;
}

#define EPI_BF16 0
#define EPI_GELU 1
#define EPI_F32  2
#define EPI_RES  3

// ---------------- LDS-staged MFMA GEMM (m97 structure) ----------------
// out[M,N] = A[M,K] @ W[N,K]^T + bias. M%128==0, N%128==0, K%32==0.
// 256 threads = 4 waves in 2x2; each wave computes 64x64 via 4x4 16x16 tiles.
template<int EPI>
__global__ __launch_bounds__(256) void gemm_lds(const u16* __restrict__ A, int lda,
                                                const u16* __restrict__ W, int ldw,
                                                const float* __restrict__ bias,
                                                u16* __restrict__ outb, float* __restrict__ outf,
                                                int ldo, int N, int K){
  __shared__ __align__(16) u16 As[128 * 32];   // [row][k], 32-wide rows, lane-linear
  __shared__ __align__(16) u16 Bs[128 * 32];
  int tid = threadIdx.x;
  int wv = tid >> 6, lane = tid & 63, l15 = lane & 15, quad = lane >> 4;
  int wm = wv & 1, wn = wv >> 1;
  int tm = blockIdx.x * 128, tn = blockIdx.y * 128;
  int r4 = lane >> 2, c8 = (lane & 3) * 8;
  const u16* Ab0 = A + (size_t)(tm + wv * 16 + r4) * lda + c8;
  const u16* Ab1 = Ab0 + (size_t)64 * lda;
  const u16* Bb0 = W + (size_t)(tn + wv * 16 + r4) * ldw + c8;
  const u16* Bb1 = Bb0 + (size_t)64 * ldw;
  u16* lA0 = &As[(size_t)wv * 512];         // 16 rows * 32 = 512 elems per chunk
  u16* lA1 = &As[(size_t)(wv + 4) * 512];
  u16* lB0 = &Bs[(size_t)wv * 512];
  u16* lB1 = &Bs[(size_t)(wv + 4) * 512];

  f32x4 acc[4][4] = {};
  for (int kt = 0; kt < K; kt += 32){
    __syncthreads();
    gload16(Ab0 + kt, lA0, lane);
    gload16(Ab1 + kt, lA1, lane);
    gload16(Bb0 + kt, lB0, lane);
    gload16(Bb1 + kt, lB1, lane);
    __syncthreads();
    s16x8 a[4], b[4];
    #pragma unroll
    for (int i = 0; i < 4; i++)
      a[i] = *(const s16x8*)&As[(size_t)(wm * 64 + i * 16 + l15) * 32 + quad * 8];
    #pragma unroll
    for (int j = 0; j < 4; j++)
      b[j] = *(const s16x8*)&Bs[(size_t)(wn * 64 + j * 16 + l15) * 32 + quad * 8];
    #pragma unroll
    for (int i = 0; i < 4; i++)
      #pragma unroll
      for (int j = 0; j < 4; j++)
        acc[i][j] = __builtin_amdgcn_mfma_f32_16x16x32_bf16(a[i], b[j], acc[i][j], 0, 0, 0);
  }
  // epilogue: C/D layout col=l15, row=quad*4+r
  #pragma unroll
  for (int j = 0; j < 4; j++){
    int col = tn + wn * 64 + j * 16 + l15;
    float bv = bias ? bias[col] : 0.0f;
    #pragma unroll
    for (int i = 0; i < 4; i++){
      int row0 = tm + wm * 64 + i * 16 + quad * 4;
      #pragma unroll
      for (int r = 0; r < 4; r++){
        float v = acc[i][j][r] + bv;
        size_t idx = (size_t)(row0 + r) * ldo + col;
        if (EPI == EPI_BF16){
          outb[idx] = f2bf(v);
        } else if (EPI == EPI_GELU){
          float gv = 0.5f * v * (1.0f + erff(v * 0.7071067811865475f));
          outb[idx] = f2bf(gv);
        } else if (EPI == EPI_F32){
          outf[idx] = v;
        } else {
          outf[idx] += v;
        }
      }
    }
  }
}

// ---------------- small-N GEMM (head only): register-direct ----------------
template<int EPI>
__global__ __launch_bounds__(256) void gemm_bt(const u16* __restrict__ A, int lda,
                                               const u16* __restrict__ W, int ldw,
                                               const float* __restrict__ bias,
                                               u16* __restrict__ outb, float* __restrict__ outf,
                                               int ldo, int N, int K){
  int wave = threadIdx.x >> 6, lane = threadIdx.x & 63;
  int l15 = lane & 15, quad = lane >> 4;
  int tm = blockIdx.x * 64 + wave * 16;
  int tn = blockIdx.y * 64;
  const u16* Ap = A + (size_t)(tm + l15) * lda + quad * 8;
  const u16* Wp0; const u16* Wp1; const u16* Wp2; const u16* Wp3;
  {
    int c0 = tn + 0*16 + l15;  int c1 = tn + 1*16 + l15;
    int c2 = tn + 2*16 + l15;  int c3 = tn + 3*16 + l15;
    Wp0 = W + (size_t)(c0 < N ? c0 : N - 1) * ldw + quad * 8;
    Wp1 = W + (size_t)(c1 < N ? c1 : N - 1) * ldw + quad * 8;
    Wp2 = W + (size_t)(c2 < N ? c2 : N - 1) * ldw + quad * 8;
    Wp3 = W + (size_t)(c3 < N ? c3 : N - 1) * ldw + quad * 8;
  }
  f32x4 acc0 = {0,0,0,0}, acc1 = {0,0,0,0}, acc2 = {0,0,0,0}, acc3 = {0,0,0,0};
  for (int k = 0; k < K; k += 32){
    s16x8 a  = *(const s16x8*)(Ap + k);
    s16x8 b0 = *(const s16x8*)(Wp0 + k);
    s16x8 b1 = *(const s16x8*)(Wp1 + k);
    s16x8 b2 = *(const s16x8*)(Wp2 + k);
    s16x8 b3 = *(const s16x8*)(Wp3 + k);
    acc0 = __builtin_amdgcn_mfma_f32_16x16x32_bf16(a, b0, acc0, 0, 0, 0);
    acc1 = __builtin_amdgcn_mfma_f32_16x16x32_bf16(a, b1, acc1, 0, 0, 0);
    acc2 = __builtin_amdgcn_mfma_f32_16x16x32_bf16(a, b2, acc2, 0, 0, 0);
    acc3 = __builtin_amdgcn_mfma_f32_16x16x32_bf16(a, b3, acc3, 0, 0, 0);
  }
  f32x4 accs[4] = {acc0, acc1, acc2, acc3};
  #pragma unroll
  for (int j = 0; j < 4; j++){
    int col = tn + j * 16 + l15;
    if (col >= N) continue;
    float bv = bias ? bias[col] : 0.0f;
    #pragma unroll
    for (int r = 0; r < 4; r++){
      int row = tm + quad * 4 + r;
      float v = accs[j][r] + bv;
      size_t idx = (size_t)row * ldo + col;
      if (EPI == EPI_BF16){
        outb[idx] = f2bf(v);
      } else if (EPI == EPI_GELU){
        float gv = 0.5f * v * (1.0f + erff(v * 0.7071067811865475f));
        outb[idx] = f2bf(gv);
      } else if (EPI == EPI_F32){
        outf[idx] = v;
      } else {
        outf[idx] += v;
      }
    }
  }
}

// ---------------- MFMA flash attention ----------------
// grid (T/64=8, B*NH=256); block 256 (4 waves, 16 q-rows each). kv len 512, dh=64.
__global__ __launch_bounds__(256) void attn_mfma(const u16* __restrict__ Qp, int qstride,
                                                 const u16* __restrict__ Kp,
                                                 const u16* __restrict__ Vp, int kvstride,
                                                 u16* __restrict__ Op){
  __shared__ __align__(16) u16 Ks[64][72];     // [kv][d]
  __shared__ __align__(16) u16 Vt[64][72];     // [d][kv], kv-blocks XOR-swizzled by (d>>3)&7
  __shared__ __align__(16) u16 Ps[4][16][72];  // per-wave P  [q][kv]
  int bh = blockIdx.y;
  int b = bh >> 3, h = bh & 7;
  int q0 = blockIdx.x * 64;
  int tid = threadIdx.x;
  int wv = tid >> 6, lane = tid & 63, l15 = lane & 15, quad = lane >> 4;
  const u16* Qb = Qp + (size_t)(b * 512 + q0 + wv * 16) * qstride + h * 64;
  const u16* Kb = Kp + (size_t)(b * 512) * kvstride + h * 64;
  const u16* Vb = Vp + (size_t)(b * 512) * kvstride + h * 64;
  s16x8 qa0 = *(const s16x8*)(Qb + (size_t)l15 * qstride + quad * 8);
  s16x8 qa1 = *(const s16x8*)(Qb + (size_t)l15 * qstride + 32 + quad * 8);

  f32x4 o0 = {0,0,0,0}, o1 = {0,0,0,0}, o2 = {0,0,0,0}, o3 = {0,0,0,0};
  f32x4 m = {-3e38f, -3e38f, -3e38f, -3e38f};
  f32x4 l = {0,0,0,0};

  for (int kt = 0; kt < 512; kt += 64){
    __syncthreads();
    for (int i = tid; i < 512; i += 256){
      int r = i >> 3, c8 = i & 7;
      u16x8 kv8 = *(const u16x8*)(Kb + (size_t)(kt + r) * kvstride + c8 * 8);
      *(u16x8*)(&Ks[r][c8 * 8]) = kv8;
      u16x8 vv8 = *(const u16x8*)(Vb + (size_t)(kt + r) * kvstride + c8 * 8);
      int col = (((r >> 3) ^ c8) << 3) + (r & 7);
      #pragma unroll
      for (int j = 0; j < 8; j++) Vt[c8 * 8 + j][col] = vv8[j];
    }
    __syncthreads();
    f32x4 st[4];
    #pragma unroll
    for (int t = 0; t < 4; t++){
      s16x8 kb0 = *(const s16x8*)(&Ks[t * 16 + l15][quad * 8]);
      s16x8 kb1 = *(const s16x8*)(&Ks[t * 16 + l15][32 + quad * 8]);
      f32x4 acc = {0,0,0,0};
      acc = __builtin_amdgcn_mfma_f32_16x16x32_bf16(qa0, kb0, acc, 0, 0, 0);
      acc = __builtin_amdgcn_mfma_f32_16x16x32_bf16(qa1, kb1, acc, 0, 0, 0);
      st[t] = acc * 0.125f;
    }
    f32x4 rowm;
    #pragma unroll
    for (int r = 0; r < 4; r++)
      rowm[r] = fmaxf(fmaxf(st[0][r], st[1][r]), fmaxf(st[2][r], st[3][r]));
    #pragma unroll
    for (int off = 1; off < 16; off <<= 1){
      #pragma unroll
      for (int r = 0; r < 4; r++) rowm[r] = fmaxf(rowm[r], __shfl_xor(rowm[r], off));
    }
    f32x4 alpha, rs = {0,0,0,0};
    float p[4][4];
    #pragma unroll
    for (int r = 0; r < 4; r++){
      float mn = fmaxf(m[r], rowm[r]);
      alpha[r] = __expf(m[r] - mn);
      m[r] = mn;
    }
    #pragma unroll
    for (int t = 0; t < 4; t++){
      #pragma unroll
      for (int r = 0; r < 4; r++){
        p[t][r] = __expf(st[t][r] - m[r]);
        rs[r] += p[t][r];
      }
    }
    #pragma unroll
    for (int off = 1; off < 16; off <<= 1){
      #pragma unroll
      for (int r = 0; r < 4; r++) rs[r] += __shfl_xor(rs[r], off);
    }
    #pragma unroll
    for (int r = 0; r < 4; r++) l[r] = l[r] * alpha[r] + rs[r];
    #pragma unroll
    for (int r = 0; r < 4; r++){
      o0[r] *= alpha[r]; o1[r] *= alpha[r]; o2[r] *= alpha[r]; o3[r] *= alpha[r];
    }
    #pragma unroll
    for (int t = 0; t < 4; t++){
      #pragma unroll
      for (int r = 0; r < 4; r++)
        Ps[wv][quad * 4 + r][t * 16 + l15] = f2bf(p[t][r]);
    }
    __syncthreads();
    s16x8 pa0 = *(const s16x8*)(&Ps[wv][l15][quad * 8]);
    s16x8 pa1 = *(const s16x8*)(&Ps[wv][l15][32 + quad * 8]);
    #pragma unroll
    for (int u = 0; u < 4; u++){
      int d0 = u * 16 + l15;
      int sw = (d0 >> 3) & 7;
      s16x8 vb0 = *(const s16x8*)(&Vt[d0][(quad ^ sw) << 3]);
      s16x8 vb1 = *(const s16x8*)(&Vt[d0][((quad + 4) ^ sw) << 3]);
      f32x4* ou = (u == 0) ? &o0 : (u == 1) ? &o1 : (u == 2) ? &o2 : &o3;
      *ou = __builtin_amdgcn_mfma_f32_16x16x32_bf16(pa0, vb0, *ou, 0, 0, 0);
      *ou = __builtin_amdgcn_mfma_f32_16x16x32_bf16(pa1, vb1, *ou, 0, 0, 0);
    }
  }
  f32x4 inv;
  #pragma unroll
  for (int r = 0; r < 4; r++) inv[r] = 1.0f / l[r];
  u16* ob = Op + (size_t)(b * 512 + q0 + wv * 16 + quad * 4) * 512 + h * 64 + l15;
  #pragma unroll
  for (int r = 0; r < 4; r++){
    ob[(size_t)r * 512 +  0] = f2bf(o0[r] * inv[r]);
    ob[(size_t)r * 512 + 16] = f2bf(o1[r] * inv[r]);
    ob[(size_t)r * 512 + 32] = f2bf(o2[r] * inv[r]);
    ob[(size_t)r * 512 + 48] = f2bf(o3[r] * inv[r]);
  }
}

// ---------------- forward-kinematics tail (fp32 out) ----------------
__global__ __launch_bounds__(256) void fk_kernel(const float* __restrict__ head, float* __restrict__ out){
  const int P[50] = {-1,0,1,2,3,1,5,6,1,
    4,9,10,11, 4,13,14,15, 4,17,18,19, 4,21,22,23, 4,25,26,27,
    7,29,30,31, 7,33,34,35, 7,37,38,39, 7,41,42,43, 7,45,46,47,
    8};
  int r = blockIdx.x * 256 + threadIdx.x;        // 16384 rows
  const float* o = head + (size_t)r * 102;
  float* ob = out + (size_t)r * 150;
  float g[50], px[50], py[50];
  g[0] = 0.0f; px[0] = o[100]; py[0] = o[101];
  ob[0] = px[0]; ob[1] = py[0]; ob[2] = 1.0f;
  #pragma unroll
  for (int j = 1; j < 50; j++){
    int p = P[j];
    float gc = g[p] + o[j];
    g[j] = gc;
    float sc = o[50 + j];
    float sn = sinf(gc), cs = cosf(gc);
    px[j] = px[p] + cs * sc;
    py[j] = py[p] + sn * sc;
    ob[3 * j] = px[j]; ob[3 * j + 1] = py[j]; ob[3 * j + 2] = 1.0f;
  }
}

extern "C" void kernel_launch(void* const* d_in, const int* in_sizes, int n_in,
                              void* d_out, int out_size, void* d_ws, size_t ws_size,
                              hipStream_t stream){
  (void)in_sizes; (void)n_in; (void)out_size; (void)ws_size;
  const float* memory   = (const float*)d_in[0];
  const float* in_w     = (const float*)d_in[1];
  const float* in_b     = (const float*)d_in[2];
  const float* conv_w   = (const float*)d_in[3];
  const float* conv_b   = (const float*)d_in[4];
  const float* qemb     = (const float*)d_in[5];
  const float* sa_in_w  = (const float*)d_in[6];
  const float* sa_in_b  = (const float*)d_in[7];
  const float* sa_out_w = (const float*)d_in[8];
  const float* sa_out_b = (const float*)d_in[9];
  const float* ca_in_w  = (const float*)d_in[10];
  const float* ca_in_b  = (const float*)d_in[11];
  const float* ca_out_w = (const float*)d_in[12];
  const float* ca_out_b = (const float*)d_in[13];
  const float* ln1_g    = (const float*)d_in[14];
  const float* ln1_b    = (const float*)d_in[15];
  const float* ln2_g    = (const float*)d_in[16];
  const float* ln2_b    = (const float*)d_in[17];
  const float* ln3_g    = (const float*)d_in[18];
  const float* ln3_b    = (const float*)d_in[19];
  const float* ff1_w    = (const float*)d_in[20];
  const float* ff1_b    = (const float*)d_in[21];
  const float* ff2_w    = (const float*)d_in[22];
  const float* ff2_b    = (const float*)d_in[23];
  const float* out_w    = (const float*)d_in[24];
  const float* out_b    = (const float*)d_in[25];

  char* ws = (char*)d_ws;
  float* pe    = (float*)(ws);                    //  1,048,576 B
  float* x     = (float*)(ws + 1048576);          // 33,554,432 B (fp32 residual)
  u16*   memb  = (u16*)  (ws + 34603008);         // 16,777,216 B
  u16*   hb    = (u16*)  (ws + 51380224);         // 16,777,216 B (LN out / attn out)
  u16*   wp    = (u16*)  (ws + 68157440);         // 36,280,320 B bf16 weight pool
  char*  big   =          ws + 104857600;         // 50,331,648 B phase-shared (end 155,189,248)

  // weight pool offsets (elements)
  u16* w_in    = wp + 0;          // 262,144
  u16* w_convt = wp + 262144;     // 1,048,576
  u16* w_sain  = wp + 1310720;    // 3,145,728
  u16* w_saout = wp + 4456448;    // 1,048,576
  u16* w_cain  = wp + 5505024;    // 3,145,728
  u16* w_caout = wp + 8650752;    // 1,048,576
  u16* w_ff1   = wp + 9699328;    // 4,194,304
  u16* w_ff2   = wp + 13893632;   // 4,194,304
  u16* w_out   = wp + 18087936;   // 52,224

  // big-region phase views
  u16* mcast   = (u16*)big;                       // 4096x512 bf16 (conv phase)
  u16* mb      = (u16*)(big + 4194304);           // 4096x512
  u16* convlin = (u16*)(big + 8388608);           // 4096x2048
  u16* qkv = (u16*)big;                           // 16384x1536 (SA phase)
  u16* qb  = (u16*)big;                           // 16384x512  (CA phase)
  u16* kvb = (u16*)(big + 16777216);              // 16384x1024 (CA phase)
  u16* f1b = (u16*)big;                           // 8192x2048  (FF phase, half rows)
  float* head = (float*)big;                      // 16384x102 fp32 (head phase)

  dim3 blk(256);
  // ---- prologue: casts + pe ----
  pe_kernel<<<1024, blk, 0, stream>>>(pe);
  castf2b_v4<<<2048,  blk, 0, stream>>>(memory,   mcast,   524288);
  castf2b_v4<<<256,   blk, 0, stream>>>(in_w,     w_in,    65536);
  convw_t_kernel<<<4096, blk, 0, stream>>>(conv_w, w_convt);
  castf2b_v4<<<3072,  blk, 0, stream>>>(sa_in_w,  w_sain,  786432);
  castf2b_v4<<<1024,  blk, 0, stream>>>(sa_out_w, w_saout, 262144);
  castf2b_v4<<<3072,  blk, 0, stream>>>(ca_in_w,  w_cain,  786432);
  castf2b_v4<<<1024,  blk, 0, stream>>>(ca_out_w, w_caout, 262144);
  castf2b_v4<<<4096,  blk, 0, stream>>>(ff1_w,    w_ff1,   1048576);
  castf2b_v4<<<4096,  blk, 0, stream>>>(ff2_w,    w_ff2,   1048576);
  castf2b_v4<<<51,    blk, 0, stream>>>(out_w,    w_out,   13056);
  initx_kernel<<<32768, blk, 0, stream>>>(qemb, pe, x);
  // m = memory @ in_proj_w^T + b     (4096 x 512)
  gemm_lds<EPI_BF16><<<dim3(32, 4),  blk, 0, stream>>>(mcast, 512, w_in, 512, in_b, mb, nullptr, 512, 512, 512);
  // convlin = m @ convwt^T           (4096 x 2048)
  gemm_lds<EPI_BF16><<<dim3(32, 16), blk, 0, stream>>>(mb, 512, w_convt, 512, nullptr, convlin, nullptr, 2048, 2048, 512);
  mem_kernel<<<32768, blk, 0, stream>>>(convlin, conv_b, pe, memb);

  for (int l = 0; l < 4; l++){
    // ---- self attention ----
    ln_kernel<<<4096, blk, 0, stream>>>(x, ln1_g + l*512, ln1_b + l*512, hb);
    gemm_lds<EPI_BF16><<<dim3(128, 12), blk, 0, stream>>>(hb, 512, w_sain + (size_t)l*786432, 512,
                                                          sa_in_b + l*1536, qkv, nullptr, 1536, 1536, 512);
    attn_mfma<<<dim3(8, 256), blk, 0, stream>>>(qkv, 1536, qkv + 512, qkv + 1024, 1536, hb);
    gemm_lds<EPI_RES><<<dim3(128, 4), blk, 0, stream>>>(hb, 512, w_saout + (size_t)l*262144, 512,
                                                        sa_out_b + l*512, nullptr, x, 512, 512, 512);
    // ---- cross attention ----
    ln_kernel<<<4096, blk, 0, stream>>>(x, ln2_g + l*512, ln2_b + l*512, hb);
    gemm_lds<EPI_BF16><<<dim3(128, 4),  blk, 0, stream>>>(hb, 512, w_cain + (size_t)l*786432, 512,
                                                          ca_in_b + l*1536, qb, nullptr, 512, 512, 512);
    gemm_lds<EPI_BF16><<<dim3(128, 8), blk, 0, stream>>>(memb, 512, w_cain + (size_t)l*786432 + 262144, 512,
                                                         ca_in_b + l*1536 + 512, kvb, nullptr, 1024, 1024, 512);
    attn_mfma<<<dim3(8, 256), blk, 0, stream>>>(qb, 512, kvb, kvb + 512, 1024, hb);
    gemm_lds<EPI_RES><<<dim3(128, 4), blk, 0, stream>>>(hb, 512, w_caout + (size_t)l*262144, 512,
                                                        ca_out_b + l*512, nullptr, x, 512, 512, 512);
    // ---- feed forward (two row-halves to bound scratch) ----
    ln_kernel<<<4096, blk, 0, stream>>>(x, ln3_g + l*512, ln3_b + l*512, hb);
    for (int h2 = 0; h2 < 2; h2++){
      size_t ro = (size_t)h2 * 8192;
      gemm_lds<EPI_GELU><<<dim3(64, 16), blk, 0, stream>>>(hb + ro*512, 512, w_ff1 + (size_t)l*1048576, 512,
                                                           ff1_b + l*2048, f1b, nullptr, 2048, 2048, 512);
      gemm_lds<EPI_RES><<<dim3(64, 4), blk, 0, stream>>>(f1b, 2048, w_ff2 + (size_t)l*1048576, 2048,
                                                         ff2_b + l*512, nullptr, x + ro*512, 512, 512, 2048);
    }
  }
  cast_kernel<<<32768, blk, 0, stream>>>(x, hb);
  gemm_bt<EPI_F32><<<dim3(256, 2), blk, 0, stream>>>(hb, 512, w_out, 512, out_b, nullptr, head, 102, 102, 512);
  fk_kernel<<<64, blk, 0, stream>>>(head, (float*)d_out);
}

// Round 6
// 2283.635 us; speedup vs baseline: 3.6525x; 1.0376x over previous
//
#include <hip/hip_runtime.h>
#include <cstdint>

typedef unsigned short u16;
typedef short s16x8 __attribute__((ext_vector_type(8)));
typedef u16   u16x4 __attribute__((ext_vector_type(4)));
typedef u16   u16x8 __attribute__((ext_vector_type(8)));
typedef float f32x4 __attribute__((ext_vector_type(4)));

__device__ __forceinline__ float bf2f(u16 u){
  union { unsigned int i; float f; } v; v.i = ((unsigned int)u) << 16; return v.f;
}
__device__ __forceinline__ u16 f2bf(float f){
  union { float f; unsigned int i; } v; v.f = f;
  unsigned int r = v.i + 0x7fffu + ((v.i >> 16) & 1u);
  return (u16)(r >> 16);
}

// async global->LDS, 16B per lane. LDS dst is wave-uniform base + lane*16.
__device__ __forceinline__ void gload16(const u16* g, u16* l, int lane){
#if __has_builtin(__builtin_amdgcn_global_load_lds)
  (void)lane;
  __builtin_amdgcn_global_load_lds((const __attribute__((address_space(1))) void*)g,
                                   (__attribute__((address_space(3))) void*)l, 16, 0, 0);
#else
  *(u16x8*)(l + lane * 8) = *(const u16x8*)g;
#endif
}

// ---------------- fp32 -> bf16 cast (vectorized), n multiple of 4 ----------------
__global__ __launch_bounds__(256) void castf2b_v4(const float* __restrict__ src,
                                                  u16* __restrict__ dst, int n4){
  int i = blockIdx.x * 256 + threadIdx.x;
  if (i >= n4) return;
  f32x4 v = *(const f32x4*)(src + i * 4);
  u16x4 o;
  o[0] = f2bf(v[0]); o[1] = f2bf(v[1]); o[2] = f2bf(v[2]); o[3] = f2bf(v[3]);
  *(u16x4*)(dst + i * 4) = o;
}

// ---------------- positional encoding (fp32) ----------------
__global__ __launch_bounds__(256) void pe_kernel(float* __restrict__ pe){
  int idx = blockIdx.x * 256 + threadIdx.x;       // 512*512
  int t = idx >> 9, h = idx & 511;
  int i2 = h >> 1;
  float freq = expf((float)(2 * i2) * (-9.210340371976184f / 512.0f));
  float a = (float)t * freq;
  pe[idx] = (h & 1) ? cosf(a) : sinf(a);
}

// ---------------- transpose+cast conv_w (C,D,K) fp32 -> (K*D, C) bf16 ----------------
__global__ __launch_bounds__(256) void convw_t_kernel(const float* __restrict__ w, u16* __restrict__ wt){
  int idx = blockIdx.x * 256 + threadIdx.x;       // 2048*512, idx = n*512 + c
  int n = idx >> 9, c = idx & 511;                // n = k*512 + d
  int k = n >> 9, d = n & 511;
  wt[idx] = f2bf(w[c * 2048 + d * 4 + k]);
}

// ---------------- x = query_emb + pe (fp32 residual stream) ----------------
__global__ __launch_bounds__(256) void initx_kernel(const float* __restrict__ qe,
                                                    const float* __restrict__ pe,
                                                    float* __restrict__ x){
  int idx = blockIdx.x * 256 + threadIdx.x;       // 32*512*512
  int th = idx & (512 * 512 - 1);
  x[idx] = qe[th] + pe[th];
}

// ---------------- mem[b, s*4+k, d] = convlin[b*128+s, k*512+d] + conv_b[d] + pe ----------------
__global__ __launch_bounds__(256) void mem_kernel(const u16* __restrict__ lin,
                                                  const float* __restrict__ cb,
                                                  const float* __restrict__ pe,
                                                  u16* __restrict__ mem){
  int idx = blockIdx.x * 256 + threadIdx.x;       // 32*512*512
  int d = idx & 511;
  int t = (idx >> 9) & 511;
  int b = idx >> 18;
  int s = t >> 2, k = t & 3;
  float v = bf2f(lin[(size_t)(b * 128 + s) * 2048 + k * 512 + d]) + cb[d] + pe[t * 512 + d];
  mem[idx] = f2bf(v);
}

// ---------------- cast fp32 -> bf16 ----------------
__global__ __launch_bounds__(256) void cast_kernel(const float* __restrict__ x, u16* __restrict__ o){
  int idx = blockIdx.x * 256 + threadIdx.x;
  o[idx] = f2bf(x[idx]);
}

// ---------------- LayerNorm: fp32 x -> bf16 out ----------------
__global__ __launch_bounds__(256) void ln_kernel(const float* __restrict__ x,
                                                 const float* __restrict__ g,
                                                 const float* __restrict__ bta,
                                                 u16* __restrict__ out){
  int wave = threadIdx.x >> 6, lane = threadIdx.x & 63;
  size_t row = (size_t)blockIdx.x * 4 + wave;
  const float* xr = x + row * 512 + lane * 8;
  f32x4 v0 = *(const f32x4*)xr;
  f32x4 v1 = *(const f32x4*)(xr + 4);
  float s  = v0[0]+v0[1]+v0[2]+v0[3] + v1[0]+v1[1]+v1[2]+v1[3];
  float s2 = v0[0]*v0[0]+v0[1]*v0[1]+v0[2]*v0[2]+v0[3]*v0[3]
           + v1[0]*v1[0]+v1[1]*v1[1]+v1[2]*v1[2]+v1[3]*v1[3];
  #pragma unroll
  for (int off = 1; off < 64; off <<= 1){
    s  += __shfl_xor(s, off);
    s2 += __shfl_xor(s2, off);
  }
  float mean = s * (1.0f / 512.0f);
  float var  = s2 * (1.0f / 512.0f) - mean * mean;
  float rstd = rsqrtf(var + 1e-5f);
  int c = lane * 8;
  u16x8 o;
  #pragma unroll
  for (int j = 0; j < 8; j++){
    float xv = (j < 4) ? v0[j] : v1[j - 4];
    o[j] = f2bf((xv - mean) * rstd * g[c + j] + bta[c + j]);
  }
  *(u16x8*)(out + row * 512 + c) = o;
}

#define EPI_BF16 0
#define EPI_GELU 1
#define EPI_F32  2
#define EPI_RES  3
#define EPI_QKVT 4   // cols < vcol0 -> outb normal (ldo==vcol0); cols >= vcol0 -> V^T scatter

// ---------------- LDS-staged MFMA GEMM (m97 structure) ----------------
// out[M,N] = A[M,K] @ W[N,K]^T + bias. M%128==0, N%128==0, K%32==0.
template<int EPI>
__global__ __launch_bounds__(256) void gemm_lds(const u16* __restrict__ A, int lda,
                                                const u16* __restrict__ W, int ldw,
                                                const float* __restrict__ bias,
                                                u16* __restrict__ outb, float* __restrict__ outf,
                                                int ldo, int N, int K,
                                                u16* __restrict__ vt, int vcol0){
  __shared__ __align__(16) u16 As[128 * 32];   // [row][k], 32-wide rows, lane-linear
  __shared__ __align__(16) u16 Bs[128 * 32];
  int tid = threadIdx.x;
  int wv = tid >> 6, lane = tid & 63, l15 = lane & 15, quad = lane >> 4;
  int wm = wv & 1, wn = wv >> 1;
  int tm = blockIdx.x * 128, tn = blockIdx.y * 128;
  int r4 = lane >> 2, c8 = (lane & 3) * 8;
  const u16* Ab0 = A + (size_t)(tm + wv * 16 + r4) * lda + c8;
  const u16* Ab1 = Ab0 + (size_t)64 * lda;
  const u16* Bb0 = W + (size_t)(tn + wv * 16 + r4) * ldw + c8;
  const u16* Bb1 = Bb0 + (size_t)64 * ldw;
  u16* lA0 = &As[(size_t)wv * 512];
  u16* lA1 = &As[(size_t)(wv + 4) * 512];
  u16* lB0 = &Bs[(size_t)wv * 512];
  u16* lB1 = &Bs[(size_t)(wv + 4) * 512];

  f32x4 acc[4][4] = {};
  for (int kt = 0; kt < K; kt += 32){
    __syncthreads();
    gload16(Ab0 + kt, lA0, lane);
    gload16(Ab1 + kt, lA1, lane);
    gload16(Bb0 + kt, lB0, lane);
    gload16(Bb1 + kt, lB1, lane);
    __syncthreads();
    s16x8 a[4], b[4];
    #pragma unroll
    for (int i = 0; i < 4; i++)
      a[i] = *(const s16x8*)&As[(size_t)(wm * 64 + i * 16 + l15) * 32 + quad * 8];
    #pragma unroll
    for (int j = 0; j < 4; j++)
      b[j] = *(const s16x8*)&Bs[(size_t)(wn * 64 + j * 16 + l15) * 32 + quad * 8];
    #pragma unroll
    for (int i = 0; i < 4; i++)
      #pragma unroll
      for (int j = 0; j < 4; j++)
        acc[i][j] = __builtin_amdgcn_mfma_f32_16x16x32_bf16(a[i], b[j], acc[i][j], 0, 0, 0);
  }
  // epilogue: C/D layout col=l15, row=quad*4+r
  #pragma unroll
  for (int j = 0; j < 4; j++){
    int col = tn + wn * 64 + j * 16 + l15;
    float bv = bias ? bias[col] : 0.0f;
    #pragma unroll
    for (int i = 0; i < 4; i++){
      int row0 = tm + wm * 64 + i * 16 + quad * 4;
      #pragma unroll
      for (int r = 0; r < 4; r++){
        int row = row0 + r;
        float v = acc[i][j][r] + bv;
        size_t idx = (size_t)row * ldo + col;
        if (EPI == EPI_BF16){
          outb[idx] = f2bf(v);
        } else if (EPI == EPI_GELU){
          float gv = 0.5f * v * (1.0f + erff(v * 0.7071067811865475f));
          outb[idx] = f2bf(gv);
        } else if (EPI == EPI_F32){
          outf[idx] = v;
        } else if (EPI == EPI_RES){
          outf[idx] += v;
        } else { // EPI_QKVT
          if (col < vcol0){
            outb[idx] = f2bf(v);
          } else {
            int vc = col - vcol0;
            // Vt[(b*8 + head)*64 + d][kv],  b=row>>9, kv=row&511
            size_t vidx = ((size_t)((row >> 9) * 8 + (vc >> 6)) * 64 + (vc & 63)) * 512 + (row & 511);
            vt[vidx] = f2bf(v);
          }
        }
      }
    }
  }
}

// ---------------- small-N GEMM (head only): register-direct ----------------
template<int EPI>
__global__ __launch_bounds__(256) void gemm_bt(const u16* __restrict__ A, int lda,
                                               const u16* __restrict__ W, int ldw,
                                               const float* __restrict__ bias,
                                               u16* __restrict__ outb, float* __restrict__ outf,
                                               int ldo, int N, int K){
  int wave = threadIdx.x >> 6, lane = threadIdx.x & 63;
  int l15 = lane & 15, quad = lane >> 4;
  int tm = blockIdx.x * 64 + wave * 16;
  int tn = blockIdx.y * 64;
  const u16* Ap = A + (size_t)(tm + l15) * lda + quad * 8;
  const u16* Wp0; const u16* Wp1; const u16* Wp2; const u16* Wp3;
  {
    int c0 = tn + 0*16 + l15;  int c1 = tn + 1*16 + l15;
    int c2 = tn + 2*16 + l15;  int c3 = tn + 3*16 + l15;
    Wp0 = W + (size_t)(c0 < N ? c0 : N - 1) * ldw + quad * 8;
    Wp1 = W + (size_t)(c1 < N ? c1 : N - 1) * ldw + quad * 8;
    Wp2 = W + (size_t)(c2 < N ? c2 : N - 1) * ldw + quad * 8;
    Wp3 = W + (size_t)(c3 < N ? c3 : N - 1) * ldw + quad * 8;
  }
  f32x4 acc0 = {0,0,0,0}, acc1 = {0,0,0,0}, acc2 = {0,0,0,0}, acc3 = {0,0,0,0};
  for (int k = 0; k < K; k += 32){
    s16x8 a  = *(const s16x8*)(Ap + k);
    s16x8 b0 = *(const s16x8*)(Wp0 + k);
    s16x8 b1 = *(const s16x8*)(Wp1 + k);
    s16x8 b2 = *(const s16x8*)(Wp2 + k);
    s16x8 b3 = *(const s16x8*)(Wp3 + k);
    acc0 = __builtin_amdgcn_mfma_f32_16x16x32_bf16(a, b0, acc0, 0, 0, 0);
    acc1 = __builtin_amdgcn_mfma_f32_16x16x32_bf16(a, b1, acc1, 0, 0, 0);
    acc2 = __builtin_amdgcn_mfma_f32_16x16x32_bf16(a, b2, acc2, 0, 0, 0);
    acc3 = __builtin_amdgcn_mfma_f32_16x16x32_bf16(a, b3, acc3, 0, 0, 0);
  }
  f32x4 accs[4] = {acc0, acc1, acc2, acc3};
  #pragma unroll
  for (int j = 0; j < 4; j++){
    int col = tn + j * 16 + l15;
    if (col >= N) continue;
    float bv = bias ? bias[col] : 0.0f;
    #pragma unroll
    for (int r = 0; r < 4; r++){
      int row = tm + quad * 4 + r;
      float v = accs[j][r] + bv;
      size_t idx = (size_t)row * ldo + col;
      if (EPI == EPI_BF16){
        outb[idx] = f2bf(v);
      } else if (EPI == EPI_GELU){
        float gv = 0.5f * v * (1.0f + erff(v * 0.7071067811865475f));
        outb[idx] = f2bf(gv);
      } else if (EPI == EPI_F32){
        outf[idx] = v;
      } else {
        outf[idx] += v;
      }
    }
  }
}

// ---------------- MFMA flash attention, swapped-operand form ----------------
// grid (B*NH=256, T/64=8); block 256 (4 waves, 16 q-rows each). kv len 512, dh=64.
// S^T = K*Q^T (A=K, B=Q), softmax per-lane scalar (q=lane&15),
// O^T = V^T*P (A=Vt rows, B=P[q][kv] from packed LDS). Vt is pre-transposed global.
__global__ __launch_bounds__(256) void attn_mfma2(const u16* __restrict__ Qp, int qstride,
                                                  const u16* __restrict__ Kp, int kstride,
                                                  const u16* __restrict__ Vt,
                                                  u16* __restrict__ Op){
  __shared__ __align__(16) u16 Ks[64][72];     // [kv][d]
  __shared__ __align__(16) u16 Vs[64][72];     // [d][kv-tile]
  __shared__ __align__(16) u16 Pb[4][16][72];  // per-wave P [q][kv]
  int bh = blockIdx.x;
  int b = bh >> 3, h = bh & 7;
  int q0 = blockIdx.y * 64;
  int tid = threadIdx.x;
  int wv = tid >> 6, lane = tid & 63, l15 = lane & 15, quad = lane >> 4;
  const u16* Qb = Qp + (size_t)(b * 512 + q0 + wv * 16) * qstride + h * 64;
  const u16* Kb = Kp + (size_t)(b * 512) * kstride + h * 64;
  const u16* Vb = Vt + (size_t)bh * 64 * 512;
  // Q B-fragments (held across kv tiles): B[k=d][n=q] = Q[q=l15][d=quad*8+j]
  s16x8 qb0 = *(const s16x8*)(Qb + (size_t)l15 * qstride + quad * 8);
  s16x8 qb1 = *(const s16x8*)(Qb + (size_t)l15 * qstride + 32 + quad * 8);

  f32x4 o[4] = {};               // O^T d-tiles, C-layout (row=d, col=q)
  float m = -3e38f, l = 0.0f;    // per-lane scalar state (q = l15)
  int sr = tid >> 3, sc = (tid & 7) * 8;   // staging: rows sr, sr+32; col chunk sc

  for (int kt = 0; kt < 512; kt += 64){
    __syncthreads();
    *(u16x8*)&Ks[sr][sc]      = *(const u16x8*)(Kb + (size_t)(kt + sr) * kstride + sc);
    *(u16x8*)&Ks[sr + 32][sc] = *(const u16x8*)(Kb + (size_t)(kt + sr + 32) * kstride + sc);
    *(u16x8*)&Vs[sr][sc]      = *(const u16x8*)(Vb + (size_t)sr * 512 + kt + sc);
    *(u16x8*)&Vs[sr + 32][sc] = *(const u16x8*)(Vb + (size_t)(sr + 32) * 512 + kt + sc);
    __syncthreads();
    // ---- S^T tiles: rows kv (16 per tile), cols q ----
    f32x4 st[4];
    #pragma unroll
    for (int t = 0; t < 4; t++){
      s16x8 ka0 = *(const s16x8*)&Ks[t * 16 + l15][quad * 8];
      s16x8 ka1 = *(const s16x8*)&Ks[t * 16 + l15][32 + quad * 8];
      f32x4 acc = {0,0,0,0};
      acc = __builtin_amdgcn_mfma_f32_16x16x32_bf16(ka0, qb0, acc, 0, 0, 0);
      acc = __builtin_amdgcn_mfma_f32_16x16x32_bf16(ka1, qb1, acc, 0, 0, 0);
      st[t] = acc * 0.125f;
    }
    // ---- online softmax over kv (per lane: 16 values, one q) ----
    float mx = st[0][0];
    #pragma unroll
    for (int t = 0; t < 4; t++)
      #pragma unroll
      for (int r = 0; r < 4; r++) mx = fmaxf(mx, st[t][r]);
    mx = fmaxf(mx, __shfl_xor(mx, 16));
    mx = fmaxf(mx, __shfl_xor(mx, 32));
    float mn = fmaxf(m, mx);
    float alpha = __expf(m - mn);
    m = mn;
    float rs = 0.0f;
    u16x4 pk[4];
    #pragma unroll
    for (int t = 0; t < 4; t++){
      #pragma unroll
      for (int r = 0; r < 4; r++){
        float p = __expf(st[t][r] - mn);
        rs += p;
        pk[t][r] = f2bf(p);
      }
    }
    rs += __shfl_xor(rs, 16);
    rs += __shfl_xor(rs, 32);
    l = l * alpha + rs;
    #pragma unroll
    for (int u = 0; u < 4; u++) o[u] *= alpha;
    // ---- P -> per-wave LDS [q][kv], packed 8B stores; no barrier needed ----
    #pragma unroll
    for (int t = 0; t < 4; t++)
      *(u16x4*)&Pb[wv][l15][t * 16 + quad * 4] = pk[t];
    s16x8 pb0 = *(const s16x8*)&Pb[wv][l15][quad * 8];
    s16x8 pb1 = *(const s16x8*)&Pb[wv][l15][32 + quad * 8];
    // ---- O^T += V^T * P ----
    #pragma unroll
    for (int u = 0; u < 4; u++){
      s16x8 va0 = *(const s16x8*)&Vs[u * 16 + l15][quad * 8];
      s16x8 va1 = *(const s16x8*)&Vs[u * 16 + l15][32 + quad * 8];
      o[u] = __builtin_amdgcn_mfma_f32_16x16x32_bf16(va0, pb0, o[u], 0, 0, 0);
      o[u] = __builtin_amdgcn_mfma_f32_16x16x32_bf16(va1, pb1, o[u], 0, 0, 0);
    }
  }
  // epilogue: lane holds q=l15, d = u*16 + quad*4 + r  -> packed 8B stores
  float invl = 1.0f / l;
  u16* ob = Op + (size_t)(b * 512 + q0 + wv * 16 + l15) * 512 + h * 64 + quad * 4;
  #pragma unroll
  for (int u = 0; u < 4; u++){
    u16x4 pk;
    pk[0] = f2bf(o[u][0] * invl);
    pk[1] = f2bf(o[u][1] * invl);
    pk[2] = f2bf(o[u][2] * invl);
    pk[3] = f2bf(o[u][3] * invl);
    *(u16x4*)(ob + u * 16) = pk;
  }
}

// ---------------- forward-kinematics tail (fp32 out) ----------------
__global__ __launch_bounds__(256) void fk_kernel(const float* __restrict__ head, float* __restrict__ out){
  const int P[50] = {-1,0,1,2,3,1,5,6,1,
    4,9,10,11, 4,13,14,15, 4,17,18,19, 4,21,22,23, 4,25,26,27,
    7,29,30,31, 7,33,34,35, 7,37,38,39, 7,41,42,43, 7,45,46,47,
    8};
  int r = blockIdx.x * 256 + threadIdx.x;        // 16384 rows
  const float* o = head + (size_t)r * 102;
  float* ob = out + (size_t)r * 150;
  float g[50], px[50], py[50];
  g[0] = 0.0f; px[0] = o[100]; py[0] = o[101];
  ob[0] = px[0]; ob[1] = py[0]; ob[2] = 1.0f;
  #pragma unroll
  for (int j = 1; j < 50; j++){
    int p = P[j];
    float gc = g[p] + o[j];
    g[j] = gc;
    float sc = o[50 + j];
    float sn = sinf(gc), cs = cosf(gc);
    px[j] = px[p] + cs * sc;
    py[j] = py[p] + sn * sc;
    ob[3 * j] = px[j]; ob[3 * j + 1] = py[j]; ob[3 * j + 2] = 1.0f;
  }
}

extern "C" void kernel_launch(void* const* d_in, const int* in_sizes, int n_in,
                              void* d_out, int out_size, void* d_ws, size_t ws_size,
                              hipStream_t stream){
  (void)in_sizes; (void)n_in; (void)out_size; (void)ws_size;
  const float* memory   = (const float*)d_in[0];
  const float* in_w     = (const float*)d_in[1];
  const float* in_b     = (const float*)d_in[2];
  const float* conv_w   = (const float*)d_in[3];
  const float* conv_b   = (const float*)d_in[4];
  const float* qemb     = (const float*)d_in[5];
  const float* sa_in_w  = (const float*)d_in[6];
  const float* sa_in_b  = (const float*)d_in[7];
  const float* sa_out_w = (const float*)d_in[8];
  const float* sa_out_b = (const float*)d_in[9];
  const float* ca_in_w  = (const float*)d_in[10];
  const float* ca_in_b  = (const float*)d_in[11];
  const float* ca_out_w = (const float*)d_in[12];
  const float* ca_out_b = (const float*)d_in[13];
  const float* ln1_g    = (const float*)d_in[14];
  const float* ln1_b    = (const float*)d_in[15];
  const float* ln2_g    = (const float*)d_in[16];
  const float* ln2_b    = (const float*)d_in[17];
  const float* ln3_g    = (const float*)d_in[18];
  const float* ln3_b    = (const float*)d_in[19];
  const float* ff1_w    = (const float*)d_in[20];
  const float* ff1_b    = (const float*)d_in[21];
  const float* ff2_w    = (const float*)d_in[22];
  const float* ff2_b    = (const float*)d_in[23];
  const float* out_w    = (const float*)d_in[24];
  const float* out_b    = (const float*)d_in[25];

  char* ws = (char*)d_ws;
  float* pe    = (float*)(ws);                    //  1,048,576 B
  float* x     = (float*)(ws + 1048576);          // 33,554,432 B (fp32 residual)
  u16*   memb  = (u16*)  (ws + 34603008);         // 16,777,216 B
  u16*   hb    = (u16*)  (ws + 51380224);         // 16,777,216 B (LN out / attn out)
  u16*   wp    = (u16*)  (ws + 68157440);         // 36,280,320 B bf16 weight pool
  char*  big   =          ws + 104857600;         // 50,331,648 B phase-shared (end 155,189,248)

  // weight pool offsets (elements)
  u16* w_in    = wp + 0;          // 262,144
  u16* w_convt = wp + 262144;     // 1,048,576
  u16* w_sain  = wp + 1310720;    // 3,145,728
  u16* w_saout = wp + 4456448;    // 1,048,576
  u16* w_cain  = wp + 5505024;    // 3,145,728
  u16* w_caout = wp + 8650752;    // 1,048,576
  u16* w_ff1   = wp + 9699328;    // 4,194,304
  u16* w_ff2   = wp + 13893632;   // 4,194,304
  u16* w_out   = wp + 18087936;   // 52,224

  // big-region phase views
  u16* mcast   = (u16*)big;                       // 4096x512 bf16 (conv phase)
  u16* mb      = (u16*)(big + 4194304);           // 4096x512
  u16* convlin = (u16*)(big + 8388608);           // 4096x2048
  u16* qkv2 = (u16*)big;                          // 16384x1024 (SA: Q|K)       33.55 MB
  u16* qb   = (u16*)big;                          // 16384x512  (CA: Q)         16.78 MB
  u16* kvbK = (u16*)(big + 16777216);             // 16384x512  (CA: K)         16.78 MB
  u16* vtg  = (u16*)(big + 33554432);             // 256x64x512 V^T             16.78 MB
  u16* f1b  = (u16*)big;                          // 8192x2048  (FF phase, half rows)
  float* head = (float*)big;                      // 16384x102 fp32 (head phase)

  dim3 blk(256);
  // ---- prologue: casts + pe ----
  pe_kernel<<<1024, blk, 0, stream>>>(pe);
  castf2b_v4<<<2048,  blk, 0, stream>>>(memory,   mcast,   524288);
  castf2b_v4<<<256,   blk, 0, stream>>>(in_w,     w_in,    65536);
  convw_t_kernel<<<4096, blk, 0, stream>>>(conv_w, w_convt);
  castf2b_v4<<<3072,  blk, 0, stream>>>(sa_in_w,  w_sain,  786432);
  castf2b_v4<<<1024,  blk, 0, stream>>>(sa_out_w, w_saout, 262144);
  castf2b_v4<<<3072,  blk, 0, stream>>>(ca_in_w,  w_cain,  786432);
  castf2b_v4<<<1024,  blk, 0, stream>>>(ca_out_w, w_caout, 262144);
  castf2b_v4<<<4096,  blk, 0, stream>>>(ff1_w,    w_ff1,   1048576);
  castf2b_v4<<<4096,  blk, 0, stream>>>(ff2_w,    w_ff2,   1048576);
  castf2b_v4<<<51,    blk, 0, stream>>>(out_w,    w_out,   13056);
  initx_kernel<<<32768, blk, 0, stream>>>(qemb, pe, x);
  // m = memory @ in_proj_w^T + b     (4096 x 512)
  gemm_lds<EPI_BF16><<<dim3(32, 4),  blk, 0, stream>>>(mcast, 512, w_in, 512, in_b, mb, nullptr, 512, 512, 512, nullptr, 0);
  // convlin = m @ convwt^T           (4096 x 2048)
  gemm_lds<EPI_BF16><<<dim3(32, 16), blk, 0, stream>>>(mb, 512, w_convt, 512, nullptr, convlin, nullptr, 2048, 2048, 512, nullptr, 0);
  mem_kernel<<<32768, blk, 0, stream>>>(convlin, conv_b, pe, memb);

  for (int l = 0; l < 4; l++){
    // ---- self attention ----
    ln_kernel<<<4096, blk, 0, stream>>>(x, ln1_g + l*512, ln1_b + l*512, hb);
    gemm_lds<EPI_QKVT><<<dim3(128, 12), blk, 0, stream>>>(hb, 512, w_sain + (size_t)l*786432, 512,
                                                          sa_in_b + l*1536, qkv2, nullptr, 1024, 1536, 512, vtg, 1024);
    attn_mfma2<<<dim3(256, 8), blk, 0, stream>>>(qkv2, 1024, qkv2 + 512, 1024, vtg, hb);
    gemm_lds<EPI_RES><<<dim3(128, 4), blk, 0, stream>>>(hb, 512, w_saout + (size_t)l*262144, 512,
                                                        sa_out_b + l*512, nullptr, x, 512, 512, 512, nullptr, 0);
    // ---- cross attention ----
    ln_kernel<<<4096, blk, 0, stream>>>(x, ln2_g + l*512, ln2_b + l*512, hb);
    gemm_lds<EPI_BF16><<<dim3(128, 4),  blk, 0, stream>>>(hb, 512, w_cain + (size_t)l*786432, 512,
                                                          ca_in_b + l*1536, qb, nullptr, 512, 512, 512, nullptr, 0);
    gemm_lds<EPI_QKVT><<<dim3(128, 8), blk, 0, stream>>>(memb, 512, w_cain + (size_t)l*786432 + 262144, 512,
                                                         ca_in_b + l*1536 + 512, kvbK, nullptr, 512, 1024, 512, vtg, 512);
    attn_mfma2<<<dim3(256, 8), blk, 0, stream>>>(qb, 512, kvbK, 512, vtg, hb);
    gemm_lds<EPI_RES><<<dim3(128, 4), blk, 0, stream>>>(hb, 512, w_caout + (size_t)l*262144, 512,
                                                        ca_out_b + l*512, nullptr, x, 512, 512, 512, nullptr, 0);
    // ---- feed forward (two row-halves to bound scratch) ----
    ln_kernel<<<4096, blk, 0, stream>>>(x, ln3_g + l*512, ln3_b + l*512, hb);
    for (int h2 = 0; h2 < 2; h2++){
      size_t ro = (size_t)h2 * 8192;
      gemm_lds<EPI_GELU><<<dim3(64, 16), blk, 0, stream>>>(hb + ro*512, 512, w_ff1 + (size_t)l*1048576, 512,
                                                           ff1_b + l*2048, f1b, nullptr, 2048, 2048, 512, nullptr, 0);
      gemm_lds<EPI_RES><<<dim3(64, 4), blk, 0, stream>>>(f1b, 2048, w_ff2 + (size_t)l*1048576, 2048,
                                                         ff2_b + l*512, nullptr, x + ro*512, 512, 512, 2048, nullptr, 0);
    }
  }
  cast_kernel<<<32768, blk, 0, stream>>>(x, hb);
  gemm_bt<EPI_F32><<<dim3(256, 2), blk, 0, stream>>>(hb, 512, w_out, 512, out_b, nullptr, head, 102, 102, 512);
  fk_kernel<<<64, blk, 0, stream>>>(head, (float*)d_out);
}

// Round 7
// 2123.664 us; speedup vs baseline: 3.9277x; 1.0753x over previous
//
#include <hip/hip_runtime.h>
#include <cstdint>

typedef unsigned short u16;
typedef short s16x8 __attribute__((ext_vector_type(8)));
typedef u16   u16x4 __attribute__((ext_vector_type(4)));
typedef u16   u16x8 __attribute__((ext_vector_type(8)));
typedef float f32x4 __attribute__((ext_vector_type(4)));

__device__ __forceinline__ float bf2f(u16 u){
  union { unsigned int i; float f; } v; v.i = ((unsigned int)u) << 16; return v.f;
}
__device__ __forceinline__ u16 f2bf(float f){
  union { float f; unsigned int i; } v; v.f = f;
  unsigned int r = v.i + 0x7fffu + ((v.i >> 16) & 1u);
  return (u16)(r >> 16);
}

// async global->LDS, 16B per lane. LDS dst is wave-uniform base + lane*16.
__device__ __forceinline__ void gload16(const u16* g, u16* l, int lane){
#if __has_builtin(__builtin_amdgcn_global_load_lds)
  (void)lane;
  __builtin_amdgcn_global_load_lds((const __attribute__((address_space(1))) void*)g,
                                   (__attribute__((address_space(3))) void*)l, 16, 0, 0);
#else
  *(u16x8*)(l + lane * 8) = *(const u16x8*)g;
#endif
}

// ---------------- fp32 -> bf16 cast (vectorized), n multiple of 4 ----------------
__global__ __launch_bounds__(256) void castf2b_v4(const float* __restrict__ src,
                                                  u16* __restrict__ dst, int n4){
  int i = blockIdx.x * 256 + threadIdx.x;
  if (i >= n4) return;
  f32x4 v = *(const f32x4*)(src + i * 4);
  u16x4 o;
  o[0] = f2bf(v[0]); o[1] = f2bf(v[1]); o[2] = f2bf(v[2]); o[3] = f2bf(v[3]);
  *(u16x4*)(dst + i * 4) = o;
}

// ---------------- positional encoding (fp32) ----------------
__global__ __launch_bounds__(256) void pe_kernel(float* __restrict__ pe){
  int idx = blockIdx.x * 256 + threadIdx.x;       // 512*512
  int t = idx >> 9, h = idx & 511;
  int i2 = h >> 1;
  float freq = expf((float)(2 * i2) * (-9.210340371976184f / 512.0f));
  float a = (float)t * freq;
  pe[idx] = (h & 1) ? cosf(a) : sinf(a);
}

// ---------------- transpose+cast conv_w (C,D,K) fp32 -> (K*D, C) bf16 ----------------
__global__ __launch_bounds__(256) void convw_t_kernel(const float* __restrict__ w, u16* __restrict__ wt){
  int idx = blockIdx.x * 256 + threadIdx.x;       // 2048*512, idx = n*512 + c
  int n = idx >> 9, c = idx & 511;                // n = k*512 + d
  int k = n >> 9, d = n & 511;
  wt[idx] = f2bf(w[c * 2048 + d * 4 + k]);
}

// ---------------- x = query_emb + pe (fp32 residual stream) ----------------
__global__ __launch_bounds__(256) void initx_kernel(const float* __restrict__ qe,
                                                    const float* __restrict__ pe,
                                                    float* __restrict__ x){
  int idx = blockIdx.x * 256 + threadIdx.x;       // 32*512*512
  int th = idx & (512 * 512 - 1);
  x[idx] = qe[th] + pe[th];
}

// ---------------- mem[b, s*4+k, d] = convlin[b*128+s, k*512+d] + conv_b[d] + pe ----------------
__global__ __launch_bounds__(256) void mem_kernel(const u16* __restrict__ lin,
                                                  const float* __restrict__ cb,
                                                  const float* __restrict__ pe,
                                                  u16* __restrict__ mem){
  int idx = blockIdx.x * 256 + threadIdx.x;       // 32*512*512
  int d = idx & 511;
  int t = (idx >> 9) & 511;
  int b = idx >> 18;
  int s = t >> 2, k = t & 3;
  float v = bf2f(lin[(size_t)(b * 128 + s) * 2048 + k * 512 + d]) + cb[d] + pe[t * 512 + d];
  mem[idx] = f2bf(v);
}

// ---------------- cast fp32 -> bf16 ----------------
__global__ __launch_bounds__(256) void cast_kernel(const float* __restrict__ x, u16* __restrict__ o){
  int idx = blockIdx.x * 256 + threadIdx.x;
  o[idx] = f2bf(x[idx]);
}

// ---------------- LayerNorm: fp32 x -> bf16 out ----------------
__global__ __launch_bounds__(256) void ln_kernel(const float* __restrict__ x,
                                                 const float* __restrict__ g,
                                                 const float* __restrict__ bta,
                                                 u16* __restrict__ out){
  int wave = threadIdx.x >> 6, lane = threadIdx.x & 63;
  size_t row = (size_t)blockIdx.x * 4 + wave;
  const float* xr = x + row * 512 + lane * 8;
  f32x4 v0 = *(const f32x4*)xr;
  f32x4 v1 = *(const f32x4*)(xr + 4);
  float s  = v0[0]+v0[1]+v0[2]+v0[3] + v1[0]+v1[1]+v1[2]+v1[3];
  float s2 = v0[0]*v0[0]+v0[1]*v0[1]+v0[2]*v0[2]+v0[3]*v0[3]
           + v1[0]*v1[0]+v1[1]*v1[1]+v1[2]*v1[2]+v1[3]*v1[3];
  #pragma unroll
  for (int off = 1; off < 64; off <<= 1){
    s  += __shfl_xor(s, off);
    s2 += __shfl_xor(s2, off);
  }
  float mean = s * (1.0f / 512.0f);
  float var  = s2 * (1.0f / 512.0f) - mean * mean;
  float rstd = rsqrtf(var + 1e-5f);
  int c = lane * 8;
  u16x8 o;
  #pragma unroll
  for (int j = 0; j < 8; j++){
    float xv = (j < 4) ? v0[j] : v1[j - 4];
    o[j] = f2bf((xv - mean) * rstd * g[c + j] + bta[c + j]);
  }
  *(u16x8*)(out + row * 512 + c) = o;
}

#define EPI_BF16 0
#define EPI_GELU 1
#define EPI_F32  2
#define EPI_RES  3
#define EPI_QKVT 4   // cols < vcol0 -> outb normal (ldo==vcol0); cols >= vcol0 -> V^T packed scatter

// ---------------- LDS-staged MFMA GEMM, BK=64 (dual 32-buffers), swizzled ----------------
// out[M,N] = A[M,K] @ W[N,K]^T + bias. M%128==0, N%128==0, K%64==0.
// k-chunk swizzle: staging lane (r=lane>>2, j=lane&3) loads k-chunk (j-(r>>1))&3;
// fragment read uses cs=((quad+(l15>>1))&3)*8 -> 2-way bank aliasing (free).
template<int EPI>
__global__ __launch_bounds__(256) void gemm_lds(const u16* __restrict__ A, int lda,
                                                const u16* __restrict__ W, int ldw,
                                                const float* __restrict__ bias,
                                                u16* __restrict__ outb, float* __restrict__ outf,
                                                int ldo, int N, int K,
                                                u16* __restrict__ vt, int vcol0){
  __shared__ __align__(16) u16 As[2][128 * 32];
  __shared__ __align__(16) u16 Bs[2][128 * 32];
  int tid = threadIdx.x;
  int wv = tid >> 6, lane = tid & 63, l15 = lane & 15, quad = lane >> 4;
  int wm = wv & 1, wn = wv >> 1;
  int tm = blockIdx.x * 128, tn = blockIdx.y * 128;
  int r4 = lane >> 2, j4 = lane & 3;
  int qs = ((j4 - (r4 >> 1)) & 3) * 8;
  const u16* Ab0 = A + (size_t)(tm + wv * 16 + r4) * lda + qs;
  const u16* Ab1 = Ab0 + (size_t)64 * lda;
  const u16* Bb0 = W + (size_t)(tn + wv * 16 + r4) * ldw + qs;
  const u16* Bb1 = Bb0 + (size_t)64 * ldw;
  u16* lA0a = &As[0][(size_t)wv * 512];       u16* lA0b = &As[1][(size_t)wv * 512];
  u16* lA1a = &As[0][(size_t)(wv + 4) * 512]; u16* lA1b = &As[1][(size_t)(wv + 4) * 512];
  u16* lB0a = &Bs[0][(size_t)wv * 512];       u16* lB0b = &Bs[1][(size_t)wv * 512];
  u16* lB1a = &Bs[0][(size_t)(wv + 4) * 512]; u16* lB1b = &Bs[1][(size_t)(wv + 4) * 512];
  int cs = ((quad + (l15 >> 1)) & 3) * 8;

  f32x4 acc[4][4] = {};
  for (int kt = 0; kt < K; kt += 64){
    __syncthreads();
    gload16(Ab0 + kt,      lA0a, lane);
    gload16(Ab0 + kt + 32, lA0b, lane);
    gload16(Ab1 + kt,      lA1a, lane);
    gload16(Ab1 + kt + 32, lA1b, lane);
    gload16(Bb0 + kt,      lB0a, lane);
    gload16(Bb0 + kt + 32, lB0b, lane);
    gload16(Bb1 + kt,      lB1a, lane);
    gload16(Bb1 + kt + 32, lB1b, lane);
    __syncthreads();
    s16x8 a0[4], a1[4], b0[4], b1[4];
    #pragma unroll
    for (int i = 0; i < 4; i++){
      size_t off = (size_t)(wm * 4 + i) * 512 + l15 * 32 + cs;
      a0[i] = *(const s16x8*)&As[0][off];
      a1[i] = *(const s16x8*)&As[1][off];
    }
    #pragma unroll
    for (int j = 0; j < 4; j++){
      size_t off = (size_t)(wn * 4 + j) * 512 + l15 * 32 + cs;
      b0[j] = *(const s16x8*)&Bs[0][off];
      b1[j] = *(const s16x8*)&Bs[1][off];
    }
    #pragma unroll
    for (int i = 0; i < 4; i++)
      #pragma unroll
      for (int j = 0; j < 4; j++){
        acc[i][j] = __builtin_amdgcn_mfma_f32_16x16x32_bf16(a0[i], b0[j], acc[i][j], 0, 0, 0);
        acc[i][j] = __builtin_amdgcn_mfma_f32_16x16x32_bf16(a1[i], b1[j], acc[i][j], 0, 0, 0);
      }
  }
  // epilogue: C/D layout col=l15, row=quad*4+r
  #pragma unroll
  for (int j = 0; j < 4; j++){
    int col = tn + wn * 64 + j * 16 + l15;
    float bv = bias ? bias[col] : 0.0f;
    #pragma unroll
    for (int i = 0; i < 4; i++){
      int row0 = tm + wm * 64 + i * 16 + quad * 4;
      if (EPI == EPI_QKVT && col >= vcol0){
        int vc = col - vcol0;
        // Vt[(b*8 + head)*64 + d][kv],  b=row>>9, kv=row&511 (4 consecutive kv -> packed 8B)
        size_t vidx = ((size_t)((row0 >> 9) * 8 + (vc >> 6)) * 64 + (vc & 63)) * 512 + (row0 & 511);
        u16x4 pv;
        #pragma unroll
        for (int r = 0; r < 4; r++) pv[r] = f2bf(acc[i][j][r] + bv);
        *(u16x4*)&vt[vidx] = pv;
      } else {
        #pragma unroll
        for (int r = 0; r < 4; r++){
          float v = acc[i][j][r] + bv;
          size_t idx = (size_t)(row0 + r) * ldo + col;
          if (EPI == EPI_GELU){
            float gv = 0.5f * v * (1.0f + erff(v * 0.7071067811865475f));
            outb[idx] = f2bf(gv);
          } else if (EPI == EPI_F32){
            outf[idx] = v;
          } else if (EPI == EPI_RES){
            outf[idx] += v;
          } else {
            outb[idx] = f2bf(v);
          }
        }
      }
    }
  }
}

// ---------------- small-N GEMM (head only): register-direct ----------------
template<int EPI>
__global__ __launch_bounds__(256) void gemm_bt(const u16* __restrict__ A, int lda,
                                               const u16* __restrict__ W, int ldw,
                                               const float* __restrict__ bias,
                                               u16* __restrict__ outb, float* __restrict__ outf,
                                               int ldo, int N, int K){
  int wave = threadIdx.x >> 6, lane = threadIdx.x & 63;
  int l15 = lane & 15, quad = lane >> 4;
  int tm = blockIdx.x * 64 + wave * 16;
  int tn = blockIdx.y * 64;
  const u16* Ap = A + (size_t)(tm + l15) * lda + quad * 8;
  const u16* Wp0; const u16* Wp1; const u16* Wp2; const u16* Wp3;
  {
    int c0 = tn + 0*16 + l15;  int c1 = tn + 1*16 + l15;
    int c2 = tn + 2*16 + l15;  int c3 = tn + 3*16 + l15;
    Wp0 = W + (size_t)(c0 < N ? c0 : N - 1) * ldw + quad * 8;
    Wp1 = W + (size_t)(c1 < N ? c1 : N - 1) * ldw + quad * 8;
    Wp2 = W + (size_t)(c2 < N ? c2 : N - 1) * ldw + quad * 8;
    Wp3 = W + (size_t)(c3 < N ? c3 : N - 1) * ldw + quad * 8;
  }
  f32x4 acc0 = {0,0,0,0}, acc1 = {0,0,0,0}, acc2 = {0,0,0,0}, acc3 = {0,0,0,0};
  for (int k = 0; k < K; k += 32){
    s16x8 a  = *(const s16x8*)(Ap + k);
    s16x8 b0 = *(const s16x8*)(Wp0 + k);
    s16x8 b1 = *(const s16x8*)(Wp1 + k);
    s16x8 b2 = *(const s16x8*)(Wp2 + k);
    s16x8 b3 = *(const s16x8*)(Wp3 + k);
    acc0 = __builtin_amdgcn_mfma_f32_16x16x32_bf16(a, b0, acc0, 0, 0, 0);
    acc1 = __builtin_amdgcn_mfma_f32_16x16x32_bf16(a, b1, acc1, 0, 0, 0);
    acc2 = __builtin_amdgcn_mfma_f32_16x16x32_bf16(a, b2, acc2, 0, 0, 0);
    acc3 = __builtin_amdgcn_mfma_f32_16x16x32_bf16(a, b3, acc3, 0, 0, 0);
  }
  f32x4 accs[4] = {acc0, acc1, acc2, acc3};
  #pragma unroll
  for (int j = 0; j < 4; j++){
    int col = tn + j * 16 + l15;
    if (col >= N) continue;
    float bv = bias ? bias[col] : 0.0f;
    #pragma unroll
    for (int r = 0; r < 4; r++){
      int row = tm + quad * 4 + r;
      float v = accs[j][r] + bv;
      size_t idx = (size_t)row * ldo + col;
      if (EPI == EPI_BF16){
        outb[idx] = f2bf(v);
      } else if (EPI == EPI_GELU){
        float gv = 0.5f * v * (1.0f + erff(v * 0.7071067811865475f));
        outb[idx] = f2bf(gv);
      } else if (EPI == EPI_F32){
        outf[idx] = v;
      } else {
        outf[idx] += v;
      }
    }
  }
}

// ---------------- MFMA flash attention, swapped-operand, q-tile 128 ----------------
// grid (B*NH=256, T/128=4); block 256 (4 waves, 2x16 q-rows each). kv len 512, dh=64.
// S^T = K*Q^T, softmax per-lane scalar (q=lane&15), O^T = V^T*P. Vt pre-transposed global.
__global__ __launch_bounds__(256) void attn_mfma2(const u16* __restrict__ Qp, int qstride,
                                                  const u16* __restrict__ Kp, int kstride,
                                                  const u16* __restrict__ Vt,
                                                  u16* __restrict__ Op){
  __shared__ __align__(16) u16 Ks[64][72];     // [kv][d]
  __shared__ __align__(16) u16 Vs[64][72];     // [d][kv-tile]
  __shared__ __align__(16) u16 Pb[4][16][72];  // per-wave P [q][kv] (reused across g)
  int bh = blockIdx.x;
  int b = bh >> 3, h = bh & 7;
  int q0 = blockIdx.y * 128;
  int tid = threadIdx.x;
  int wv = tid >> 6, lane = tid & 63, l15 = lane & 15, quad = lane >> 4;
  const u16* Kb = Kp + (size_t)(b * 512) * kstride + h * 64;
  const u16* Vb = Vt + (size_t)bh * 64 * 512;
  // Q B-fragments for 2 q-groups (held across kv tiles)
  s16x8 qb0[2], qb1[2];
  #pragma unroll
  for (int g = 0; g < 2; g++){
    const u16* Qb = Qp + (size_t)(b * 512 + q0 + wv * 32 + g * 16 + l15) * qstride + h * 64;
    qb0[g] = *(const s16x8*)(Qb + quad * 8);
    qb1[g] = *(const s16x8*)(Qb + 32 + quad * 8);
  }
  f32x4 o[2][4] = {};
  float m[2] = {-3e38f, -3e38f}, l[2] = {0.0f, 0.0f};
  int sr = tid >> 3, sc = (tid & 7) * 8;

  for (int kt = 0; kt < 512; kt += 64){
    __syncthreads();
    *(u16x8*)&Ks[sr][sc]      = *(const u16x8*)(Kb + (size_t)(kt + sr) * kstride + sc);
    *(u16x8*)&Ks[sr + 32][sc] = *(const u16x8*)(Kb + (size_t)(kt + sr + 32) * kstride + sc);
    *(u16x8*)&Vs[sr][sc]      = *(const u16x8*)(Vb + (size_t)sr * 512 + kt + sc);
    *(u16x8*)&Vs[sr + 32][sc] = *(const u16x8*)(Vb + (size_t)(sr + 32) * 512 + kt + sc);
    __syncthreads();
    #pragma unroll
    for (int g = 0; g < 2; g++){
      f32x4 st[4];
      #pragma unroll
      for (int t = 0; t < 4; t++){
        s16x8 ka0 = *(const s16x8*)&Ks[t * 16 + l15][quad * 8];
        s16x8 ka1 = *(const s16x8*)&Ks[t * 16 + l15][32 + quad * 8];
        f32x4 acc = {0,0,0,0};
        acc = __builtin_amdgcn_mfma_f32_16x16x32_bf16(ka0, qb0[g], acc, 0, 0, 0);
        acc = __builtin_amdgcn_mfma_f32_16x16x32_bf16(ka1, qb1[g], acc, 0, 0, 0);
        st[t] = acc * 0.125f;
      }
      float mx = st[0][0];
      #pragma unroll
      for (int t = 0; t < 4; t++)
        #pragma unroll
        for (int r = 0; r < 4; r++) mx = fmaxf(mx, st[t][r]);
      mx = fmaxf(mx, __shfl_xor(mx, 16));
      mx = fmaxf(mx, __shfl_xor(mx, 32));
      float mn = fmaxf(m[g], mx);
      float alpha = __expf(m[g] - mn);
      m[g] = mn;
      float rs = 0.0f;
      u16x4 pk[4];
      #pragma unroll
      for (int t = 0; t < 4; t++){
        #pragma unroll
        for (int r = 0; r < 4; r++){
          float p = __expf(st[t][r] - mn);
          rs += p;
          pk[t][r] = f2bf(p);
        }
      }
      rs += __shfl_xor(rs, 16);
      rs += __shfl_xor(rs, 32);
      l[g] = l[g] * alpha + rs;
      #pragma unroll
      for (int u = 0; u < 4; u++) o[g][u] *= alpha;
      #pragma unroll
      for (int t = 0; t < 4; t++)
        *(u16x4*)&Pb[wv][l15][t * 16 + quad * 4] = pk[t];
      s16x8 pb0 = *(const s16x8*)&Pb[wv][l15][quad * 8];
      s16x8 pb1 = *(const s16x8*)&Pb[wv][l15][32 + quad * 8];
      #pragma unroll
      for (int u = 0; u < 4; u++){
        s16x8 va0 = *(const s16x8*)&Vs[u * 16 + l15][quad * 8];
        s16x8 va1 = *(const s16x8*)&Vs[u * 16 + l15][32 + quad * 8];
        o[g][u] = __builtin_amdgcn_mfma_f32_16x16x32_bf16(va0, pb0, o[g][u], 0, 0, 0);
        o[g][u] = __builtin_amdgcn_mfma_f32_16x16x32_bf16(va1, pb1, o[g][u], 0, 0, 0);
      }
    }
  }
  #pragma unroll
  for (int g = 0; g < 2; g++){
    float invl = 1.0f / l[g];
    u16* ob = Op + (size_t)(b * 512 + q0 + wv * 32 + g * 16 + l15) * 512 + h * 64 + quad * 4;
    #pragma unroll
    for (int u = 0; u < 4; u++){
      u16x4 pk;
      pk[0] = f2bf(o[g][u][0] * invl);
      pk[1] = f2bf(o[g][u][1] * invl);
      pk[2] = f2bf(o[g][u][2] * invl);
      pk[3] = f2bf(o[g][u][3] * invl);
      *(u16x4*)(ob + u * 16) = pk;
    }
  }
}

// ---------------- forward-kinematics tail (fp32 out) ----------------
__global__ __launch_bounds__(256) void fk_kernel(const float* __restrict__ head, float* __restrict__ out){
  const int P[50] = {-1,0,1,2,3,1,5,6,1,
    4,9,10,11, 4,13,14,15, 4,17,18,19, 4,21,22,23, 4,25,26,27,
    7,29,30,31, 7,33,34,35, 7,37,38,39, 7,41,42,43, 7,45,46,47,
    8};
  int r = blockIdx.x * 256 + threadIdx.x;        // 16384 rows
  const float* o = head + (size_t)r * 102;
  float* ob = out + (size_t)r * 150;
  float g[50], px[50], py[50];
  g[0] = 0.0f; px[0] = o[100]; py[0] = o[101];
  ob[0] = px[0]; ob[1] = py[0]; ob[2] = 1.0f;
  #pragma unroll
  for (int j = 1; j < 50; j++){
    int p = P[j];
    float gc = g[p] + o[j];
    g[j] = gc;
    float sc = o[50 + j];
    float sn = sinf(gc), cs = cosf(gc);
    px[j] = px[p] + cs * sc;
    py[j] = py[p] + sn * sc;
    ob[3 * j] = px[j]; ob[3 * j + 1] = py[j]; ob[3 * j + 2] = 1.0f;
  }
}

extern "C" void kernel_launch(void* const* d_in, const int* in_sizes, int n_in,
                              void* d_out, int out_size, void* d_ws, size_t ws_size,
                              hipStream_t stream){
  (void)in_sizes; (void)n_in; (void)out_size; (void)ws_size;
  const float* memory   = (const float*)d_in[0];
  const float* in_w     = (const float*)d_in[1];
  const float* in_b     = (const float*)d_in[2];
  const float* conv_w   = (const float*)d_in[3];
  const float* conv_b   = (const float*)d_in[4];
  const float* qemb     = (const float*)d_in[5];
  const float* sa_in_w  = (const float*)d_in[6];
  const float* sa_in_b  = (const float*)d_in[7];
  const float* sa_out_w = (const float*)d_in[8];
  const float* sa_out_b = (const float*)d_in[9];
  const float* ca_in_w  = (const float*)d_in[10];
  const float* ca_in_b  = (const float*)d_in[11];
  const float* ca_out_w = (const float*)d_in[12];
  const float* ca_out_b = (const float*)d_in[13];
  const float* ln1_g    = (const float*)d_in[14];
  const float* ln1_b    = (const float*)d_in[15];
  const float* ln2_g    = (const float*)d_in[16];
  const float* ln2_b    = (const float*)d_in[17];
  const float* ln3_g    = (const float*)d_in[18];
  const float* ln3_b    = (const float*)d_in[19];
  const float* ff1_w    = (const float*)d_in[20];
  const float* ff1_b    = (const float*)d_in[21];
  const float* ff2_w    = (const float*)d_in[22];
  const float* ff2_b    = (const float*)d_in[23];
  const float* out_w    = (const float*)d_in[24];
  const float* out_b    = (const float*)d_in[25];

  char* ws = (char*)d_ws;
  float* pe    = (float*)(ws);                    //  1,048,576 B
  float* x     = (float*)(ws + 1048576);          // 33,554,432 B (fp32 residual)
  u16*   memb  = (u16*)  (ws + 34603008);         // 16,777,216 B
  u16*   hb    = (u16*)  (ws + 51380224);         // 16,777,216 B (LN out / attn out)
  u16*   wp    = (u16*)  (ws + 68157440);         // 36,280,320 B bf16 weight pool
  char*  big   =          ws + 104857600;         // 50,331,648 B phase-shared (end 155,189,248)

  // weight pool offsets (elements)
  u16* w_in    = wp + 0;          // 262,144
  u16* w_convt = wp + 262144;     // 1,048,576
  u16* w_sain  = wp + 1310720;    // 3,145,728
  u16* w_saout = wp + 4456448;    // 1,048,576
  u16* w_cain  = wp + 5505024;    // 3,145,728
  u16* w_caout = wp + 8650752;    // 1,048,576
  u16* w_ff1   = wp + 9699328;    // 4,194,304
  u16* w_ff2   = wp + 13893632;   // 4,194,304
  u16* w_out   = wp + 18087936;   // 52,224

  // big-region phase views
  u16* mcast   = (u16*)big;                       // 4096x512 bf16 (conv phase)
  u16* mb      = (u16*)(big + 4194304);           // 4096x512
  u16* convlin = (u16*)(big + 8388608);           // 4096x2048
  u16* qkv2 = (u16*)big;                          // 16384x1024 (SA: Q|K)
  u16* qb   = (u16*)big;                          // 16384x512  (CA: Q)
  u16* kvbK = (u16*)(big + 16777216);             // 16384x512  (CA: K)
  u16* vtg  = (u16*)(big + 33554432);             // 256x64x512 V^T
  u16* f1b  = (u16*)big;                          // 8192x2048  (FF phase, half rows)
  float* head = (float*)big;                      // 16384x102 fp32 (head phase)

  dim3 blk(256);
  // ---- prologue: casts + pe ----
  pe_kernel<<<1024, blk, 0, stream>>>(pe);
  castf2b_v4<<<2048,  blk, 0, stream>>>(memory,   mcast,   524288);
  castf2b_v4<<<256,   blk, 0, stream>>>(in_w,     w_in,    65536);
  convw_t_kernel<<<4096, blk, 0, stream>>>(conv_w, w_convt);
  castf2b_v4<<<3072,  blk, 0, stream>>>(sa_in_w,  w_sain,  786432);
  castf2b_v4<<<1024,  blk, 0, stream>>>(sa_out_w, w_saout, 262144);
  castf2b_v4<<<3072,  blk, 0, stream>>>(ca_in_w,  w_cain,  786432);
  castf2b_v4<<<1024,  blk, 0, stream>>>(ca_out_w, w_caout, 262144);
  castf2b_v4<<<4096,  blk, 0, stream>>>(ff1_w,    w_ff1,   1048576);
  castf2b_v4<<<4096,  blk, 0, stream>>>(ff2_w,    w_ff2,   1048576);
  castf2b_v4<<<51,    blk, 0, stream>>>(out_w,    w_out,   13056);
  initx_kernel<<<32768, blk, 0, stream>>>(qemb, pe, x);
  // m = memory @ in_proj_w^T + b     (4096 x 512)
  gemm_lds<EPI_BF16><<<dim3(32, 4),  blk, 0, stream>>>(mcast, 512, w_in, 512, in_b, mb, nullptr, 512, 512, 512, nullptr, 0);
  // convlin = m @ convwt^T           (4096 x 2048)
  gemm_lds<EPI_BF16><<<dim3(32, 16), blk, 0, stream>>>(mb, 512, w_convt, 512, nullptr, convlin, nullptr, 2048, 2048, 512, nullptr, 0);
  mem_kernel<<<32768, blk, 0, stream>>>(convlin, conv_b, pe, memb);

  for (int l = 0; l < 4; l++){
    // ---- self attention ----
    ln_kernel<<<4096, blk, 0, stream>>>(x, ln1_g + l*512, ln1_b + l*512, hb);
    gemm_lds<EPI_QKVT><<<dim3(128, 12), blk, 0, stream>>>(hb, 512, w_sain + (size_t)l*786432, 512,
                                                          sa_in_b + l*1536, qkv2, nullptr, 1024, 1536, 512, vtg, 1024);
    attn_mfma2<<<dim3(256, 4), blk, 0, stream>>>(qkv2, 1024, qkv2 + 512, 1024, vtg, hb);
    gemm_lds<EPI_RES><<<dim3(128, 4), blk, 0, stream>>>(hb, 512, w_saout + (size_t)l*262144, 512,
                                                        sa_out_b + l*512, nullptr, x, 512, 512, 512, nullptr, 0);
    // ---- cross attention ----
    ln_kernel<<<4096, blk, 0, stream>>>(x, ln2_g + l*512, ln2_b + l*512, hb);
    gemm_lds<EPI_BF16><<<dim3(128, 4),  blk, 0, stream>>>(hb, 512, w_cain + (size_t)l*786432, 512,
                                                          ca_in_b + l*1536, qb, nullptr, 512, 512, 512, nullptr, 0);
    gemm_lds<EPI_QKVT><<<dim3(128, 8), blk, 0, stream>>>(memb, 512, w_cain + (size_t)l*786432 + 262144, 512,
                                                         ca_in_b + l*1536 + 512, kvbK, nullptr, 512, 1024, 512, vtg, 512);
    attn_mfma2<<<dim3(256, 4), blk, 0, stream>>>(qb, 512, kvbK, 512, vtg, hb);
    gemm_lds<EPI_RES><<<dim3(128, 4), blk, 0, stream>>>(hb, 512, w_caout + (size_t)l*262144, 512,
                                                        ca_out_b + l*512, nullptr, x, 512, 512, 512, nullptr, 0);
    // ---- feed forward (two row-halves to bound scratch) ----
    ln_kernel<<<4096, blk, 0, stream>>>(x, ln3_g + l*512, ln3_b + l*512, hb);
    for (int h2 = 0; h2 < 2; h2++){
      size_t ro = (size_t)h2 * 8192;
      gemm_lds<EPI_GELU><<<dim3(64, 16), blk, 0, stream>>>(hb + ro*512, 512, w_ff1 + (size_t)l*1048576, 512,
                                                           ff1_b + l*2048, f1b, nullptr, 2048, 2048, 512, nullptr, 0);
      gemm_lds<EPI_RES><<<dim3(64, 4), blk, 0, stream>>>(f1b, 2048, w_ff2 + (size_t)l*1048576, 2048,
                                                         ff2_b + l*512, nullptr, x + ro*512, 512, 512, 2048, nullptr, 0);
    }
  }
  cast_kernel<<<32768, blk, 0, stream>>>(x, hb);
  gemm_bt<EPI_F32><<<dim3(256, 2), blk, 0, stream>>>(hb, 512, w_out, 512, out_b, nullptr, head, 102, 102, 512);
  fk_kernel<<<64, blk, 0, stream>>>(head, (float*)d_out);
}

// Round 9
// 2063.416 us; speedup vs baseline: 4.0424x; 1.0292x over previous
//
#include <hip/hip_runtime.h>
#include <cstdint>

typedef unsigned short u16;
typedef short s16x8 __attribute__((ext_vector_type(8)));
typedef u16   u16x4 __attribute__((ext_vector_type(4)));
typedef u16   u16x8 __attribute__((ext_vector_type(8)));
typedef float f32x4 __attribute__((ext_vector_type(4)));

__device__ __forceinline__ float bf2f(u16 u){
  union { unsigned int i; float f; } v; v.i = ((unsigned int)u) << 16; return v.f;
}
__device__ __forceinline__ u16 f2bf(float f){
  union { float f; unsigned int i; } v; v.f = f;
  unsigned int r = v.i + 0x7fffu + ((v.i >> 16) & 1u);
  return (u16)(r >> 16);
}

// async global->LDS, 16B per lane. LDS dst is wave-uniform base + lane*16.
__device__ __forceinline__ void gload16(const u16* g, u16* l, int lane){
#if __has_builtin(__builtin_amdgcn_global_load_lds)
  (void)lane;
  __builtin_amdgcn_global_load_lds((const __attribute__((address_space(1))) void*)g,
                                   (__attribute__((address_space(3))) void*)l, 16, 0, 0);
#else
  *(u16x8*)(l + lane * 8) = *(const u16x8*)g;
#endif
}

// ---------------- fused fp32->bf16 cast over 9 regions ----------------
struct C9 {
  const float* s[9];
  u16* d[9];
  int e[10];   // cumulative boundaries in 4-element units
};
__global__ __launch_bounds__(256) void cast_all(C9 a){
  int i = blockIdx.x * 256 + threadIdx.x;
  if (i >= a.e[9]) return;
  int r = 0;
  #pragma unroll
  for (int k = 1; k < 9; k++) if (i >= a.e[k]) r = k;
  int loc = i - a.e[r];
  f32x4 v = *(const f32x4*)(a.s[r] + (size_t)loc * 4);
  u16x4 o;
  o[0] = f2bf(v[0]); o[1] = f2bf(v[1]); o[2] = f2bf(v[2]); o[3] = f2bf(v[3]);
  *(u16x4*)(a.d[r] + (size_t)loc * 4) = o;
}

// ---------------- positional encoding (fp32) ----------------
__global__ __launch_bounds__(256) void pe_kernel(float* __restrict__ pe){
  int idx = blockIdx.x * 256 + threadIdx.x;       // 512*512
  int t = idx >> 9, h = idx & 511;
  int i2 = h >> 1;
  float freq = expf((float)(2 * i2) * (-9.210340371976184f / 512.0f));
  float a = (float)t * freq;
  pe[idx] = (h & 1) ? cosf(a) : sinf(a);
}

// ---------------- transpose+cast conv_w (C,D,K) fp32 -> (K*D, C) bf16 ----------------
__global__ __launch_bounds__(256) void convw_t_kernel(const float* __restrict__ w, u16* __restrict__ wt){
  int idx = blockIdx.x * 256 + threadIdx.x;       // 2048*512, idx = n*512 + c
  int n = idx >> 9, c = idx & 511;                // n = k*512 + d
  int k = n >> 9, d = n & 511;
  wt[idx] = f2bf(w[c * 2048 + d * 4 + k]);
}

// ---------------- x = query_emb + pe (fp32 residual stream) ----------------
__global__ __launch_bounds__(256) void initx_kernel(const float* __restrict__ qe,
                                                    const float* __restrict__ pe,
                                                    float* __restrict__ x){
  int idx = blockIdx.x * 256 + threadIdx.x;       // 32*512*512
  int th = idx & (512 * 512 - 1);
  x[idx] = qe[th] + pe[th];
}

// ---------------- mem[b, s*4+k, d] = convlin[b*128+s, k*512+d] + conv_b[d] + pe ----------------
__global__ __launch_bounds__(256) void mem_kernel(const u16* __restrict__ lin,
                                                  const float* __restrict__ cb,
                                                  const float* __restrict__ pe,
                                                  u16* __restrict__ mem){
  int idx = blockIdx.x * 256 + threadIdx.x;       // 32*512*512
  int d = idx & 511;
  int t = (idx >> 9) & 511;
  int b = idx >> 18;
  int s = t >> 2, k = t & 3;
  float v = bf2f(lin[(size_t)(b * 128 + s) * 2048 + k * 512 + d]) + cb[d] + pe[t * 512 + d];
  mem[idx] = f2bf(v);
}

// ---------------- cast fp32 -> bf16 ----------------
__global__ __launch_bounds__(256) void cast_kernel(const float* __restrict__ x, u16* __restrict__ o){
  int idx = blockIdx.x * 256 + threadIdx.x;
  o[idx] = f2bf(x[idx]);
}

// ---------------- LayerNorm: fp32 x -> bf16 out ----------------
__global__ __launch_bounds__(256) void ln_kernel(const float* __restrict__ x,
                                                 const float* __restrict__ g,
                                                 const float* __restrict__ bta,
                                                 u16* __restrict__ out){
  int wave = threadIdx.x >> 6, lane = threadIdx.x & 63;
  size_t row = (size_t)blockIdx.x * 4 + wave;
  const float* xr = x + row * 512 + lane * 8;
  f32x4 v0 = *(const f32x4*)xr;
  f32x4 v1 = *(const f32x4*)(xr + 4);
  float s  = v0[0]+v0[1]+v0[2]+v0[3] + v1[0]+v1[1]+v1[2]+v1[3];
  float s2 = v0[0]*v0[0]+v0[1]*v0[1]+v0[2]*v0[2]+v0[3]*v0[3]
           + v1[0]*v1[0]+v1[1]*v1[1]+v1[2]*v1[2]+v1[3]*v1[3];
  #pragma unroll
  for (int off = 1; off < 64; off <<= 1){
    s  += __shfl_xor(s, off);
    s2 += __shfl_xor(s2, off);
  }
  float mean = s * (1.0f / 512.0f);
  float var  = s2 * (1.0f / 512.0f) - mean * mean;
  float rstd = rsqrtf(var + 1e-5f);
  int c = lane * 8;
  u16x8 o;
  #pragma unroll
  for (int j = 0; j < 8; j++){
    float xv = (j < 4) ? v0[j] : v1[j - 4];
    o[j] = f2bf((xv - mean) * rstd * g[c + j] + bta[c + j]);
  }
  *(u16x8*)(out + row * 512 + c) = o;
}

#define EPI_BF16 0
#define EPI_GELU 1
#define EPI_F32  2
#define EPI_RES  3
#define EPI_QKVT 4   // cols < vcol0 -> outb normal (ldo==vcol0); cols >= vcol0 -> V^T packed scatter

// ---------------- LDS-staged MFMA GEMM, BK=64, bank-swizzled, XCD-partitioned ----------------
// 1-D grid of nm*nn blocks (+ optional split-K on z). xcd=id&7 gets an m-slice, n spans all
// -> per-XCD L2 working set = A-slice + full W. k-chunk swizzle keeps LDS conflict-free.
template<int EPI>
__global__ __launch_bounds__(256) void gemm_lds(const u16* __restrict__ A, int lda,
                                                const u16* __restrict__ W, int ldw,
                                                const float* __restrict__ bias,
                                                u16* __restrict__ outb, float* __restrict__ outf,
                                                int ldo, int N, int K,
                                                u16* __restrict__ vt, int vcol0, int nm){
  __shared__ __align__(16) u16 As[2][128 * 32];
  __shared__ __align__(16) u16 Bs[2][128 * 32];
  int id = blockIdx.x;
  int xcd = id & 7, t = id >> 3;
  int nm8 = nm >> 3;
  int tm = (xcd * nm8 + (t % nm8)) * 128;
  int tn = (t / nm8) * 128;
  int tid = threadIdx.x;
  int wv = tid >> 6, lane = tid & 63, l15 = lane & 15, quad = lane >> 4;
  int wm = wv & 1, wn = wv >> 1;
  int r4 = lane >> 2, j4 = lane & 3;
  int qs = ((j4 - (r4 >> 1)) & 3) * 8;
  const u16* Ab0 = A + (size_t)(tm + wv * 16 + r4) * lda + qs;
  const u16* Ab1 = Ab0 + (size_t)64 * lda;
  const u16* Bb0 = W + (size_t)(tn + wv * 16 + r4) * ldw + qs;
  const u16* Bb1 = Bb0 + (size_t)64 * ldw;
  u16* lA0a = &As[0][(size_t)wv * 512];       u16* lA0b = &As[1][(size_t)wv * 512];
  u16* lA1a = &As[0][(size_t)(wv + 4) * 512]; u16* lA1b = &As[1][(size_t)(wv + 4) * 512];
  u16* lB0a = &Bs[0][(size_t)wv * 512];       u16* lB0b = &Bs[1][(size_t)wv * 512];
  u16* lB1a = &Bs[0][(size_t)(wv + 4) * 512]; u16* lB1b = &Bs[1][(size_t)(wv + 4) * 512];
  int cs = ((quad + (l15 >> 1)) & 3) * 8;
  // split-K
  int kz = blockIdx.z;
  int Kc = K / gridDim.z;
  int k0 = kz * Kc;

  f32x4 acc[4][4] = {};
  for (int kt = k0; kt < k0 + Kc; kt += 64){
    __syncthreads();
    gload16(Ab0 + kt,      lA0a, lane);
    gload16(Ab0 + kt + 32, lA0b, lane);
    gload16(Ab1 + kt,      lA1a, lane);
    gload16(Ab1 + kt + 32, lA1b, lane);
    gload16(Bb0 + kt,      lB0a, lane);
    gload16(Bb0 + kt + 32, lB0b, lane);
    gload16(Bb1 + kt,      lB1a, lane);
    gload16(Bb1 + kt + 32, lB1b, lane);
    __syncthreads();
    s16x8 a0[4], a1[4], b0[4], b1[4];
    #pragma unroll
    for (int i = 0; i < 4; i++){
      size_t off = (size_t)(wm * 4 + i) * 512 + l15 * 32 + cs;
      a0[i] = *(const s16x8*)&As[0][off];
      a1[i] = *(const s16x8*)&As[1][off];
    }
    #pragma unroll
    for (int j = 0; j < 4; j++){
      size_t off = (size_t)(wn * 4 + j) * 512 + l15 * 32 + cs;
      b0[j] = *(const s16x8*)&Bs[0][off];
      b1[j] = *(const s16x8*)&Bs[1][off];
    }
    #pragma unroll
    for (int i = 0; i < 4; i++)
      #pragma unroll
      for (int j = 0; j < 4; j++){
        acc[i][j] = __builtin_amdgcn_mfma_f32_16x16x32_bf16(a0[i], b0[j], acc[i][j], 0, 0, 0);
        acc[i][j] = __builtin_amdgcn_mfma_f32_16x16x32_bf16(a1[i], b1[j], acc[i][j], 0, 0, 0);
      }
  }
  // epilogue: C/D layout col=l15, row=quad*4+r
  #pragma unroll
  for (int j = 0; j < 4; j++){
    int col = tn + wn * 64 + j * 16 + l15;
    float bv = (bias && kz == 0) ? bias[col] : 0.0f;
    #pragma unroll
    for (int i = 0; i < 4; i++){
      int row0 = tm + wm * 64 + i * 16 + quad * 4;
      if (EPI == EPI_QKVT && col >= vcol0){
        int vc = col - vcol0;
        // Vt[(b*8 + head)*64 + d][kv],  b=row>>9, kv=row&511 (4 consecutive kv -> packed 8B)
        size_t vidx = ((size_t)((row0 >> 9) * 8 + (vc >> 6)) * 64 + (vc & 63)) * 512 + (row0 & 511);
        u16x4 pv;
        #pragma unroll
        for (int r = 0; r < 4; r++) pv[r] = f2bf(acc[i][j][r] + bv);
        *(u16x4*)&vt[vidx] = pv;
      } else {
        #pragma unroll
        for (int r = 0; r < 4; r++){
          float v = acc[i][j][r] + bv;
          size_t idx = (size_t)(row0 + r) * ldo + col;
          if (EPI == EPI_GELU){
            float gv = 0.5f * v * (1.0f + erff(v * 0.7071067811865475f));
            outb[idx] = f2bf(gv);
          } else if (EPI == EPI_F32){
            outf[idx] = v;
          } else if (EPI == EPI_RES){
            if (gridDim.z > 1) atomicAdd(&outf[idx], v);
            else outf[idx] += v;
          } else {
            outb[idx] = f2bf(v);
          }
        }
      }
    }
  }
}

// ---------------- small-N GEMM (head only): register-direct ----------------
template<int EPI>
__global__ __launch_bounds__(256) void gemm_bt(const u16* __restrict__ A, int lda,
                                               const u16* __restrict__ W, int ldw,
                                               const float* __restrict__ bias,
                                               u16* __restrict__ outb, float* __restrict__ outf,
                                               int ldo, int N, int K){
  int wave = threadIdx.x >> 6, lane = threadIdx.x & 63;
  int l15 = lane & 15, quad = lane >> 4;
  int tm = blockIdx.x * 64 + wave * 16;
  int tn = blockIdx.y * 64;
  const u16* Ap = A + (size_t)(tm + l15) * lda + quad * 8;
  const u16* Wp0; const u16* Wp1; const u16* Wp2; const u16* Wp3;
  {
    int c0 = tn + 0*16 + l15;  int c1 = tn + 1*16 + l15;
    int c2 = tn + 2*16 + l15;  int c3 = tn + 3*16 + l15;
    Wp0 = W + (size_t)(c0 < N ? c0 : N - 1) * ldw + quad * 8;
    Wp1 = W + (size_t)(c1 < N ? c1 : N - 1) * ldw + quad * 8;
    Wp2 = W + (size_t)(c2 < N ? c2 : N - 1) * ldw + quad * 8;
    Wp3 = W + (size_t)(c3 < N ? c3 : N - 1) * ldw + quad * 8;
  }
  f32x4 acc0 = {0,0,0,0}, acc1 = {0,0,0,0}, acc2 = {0,0,0,0}, acc3 = {0,0,0,0};
  for (int k = 0; k < K; k += 32){
    s16x8 a  = *(const s16x8*)(Ap + k);
    s16x8 b0 = *(const s16x8*)(Wp0 + k);
    s16x8 b1 = *(const s16x8*)(Wp1 + k);
    s16x8 b2 = *(const s16x8*)(Wp2 + k);
    s16x8 b3 = *(const s16x8*)(Wp3 + k);
    acc0 = __builtin_amdgcn_mfma_f32_16x16x32_bf16(a, b0, acc0, 0, 0, 0);
    acc1 = __builtin_amdgcn_mfma_f32_16x16x32_bf16(a, b1, acc1, 0, 0, 0);
    acc2 = __builtin_amdgcn_mfma_f32_16x16x32_bf16(a, b2, acc2, 0, 0, 0);
    acc3 = __builtin_amdgcn_mfma_f32_16x16x32_bf16(a, b3, acc3, 0, 0, 0);
  }
  f32x4 accs[4] = {acc0, acc1, acc2, acc3};
  #pragma unroll
  for (int j = 0; j < 4; j++){
    int col = tn + j * 16 + l15;
    if (col >= N) continue;
    float bv = bias ? bias[col] : 0.0f;
    #pragma unroll
    for (int r = 0; r < 4; r++){
      int row = tm + quad * 4 + r;
      float v = accs[j][r] + bv;
      size_t idx = (size_t)row * ldo + col;
      if (EPI == EPI_BF16){
        outb[idx] = f2bf(v);
      } else if (EPI == EPI_GELU){
        float gv = 0.5f * v * (1.0f + erff(v * 0.7071067811865475f));
        outb[idx] = f2bf(gv);
      } else if (EPI == EPI_F32){
        outf[idx] = v;
      } else {
        outf[idx] += v;
      }
    }
  }
}

// ---------------- MFMA flash attention, swapped-operand, q-tile 128 ----------------
// grid (B*NH=256, T/128=4); block 256 (4 waves, 2x16 q-rows each). kv len 512, dh=64.
__global__ __launch_bounds__(256) void attn_mfma2(const u16* __restrict__ Qp, int qstride,
                                                  const u16* __restrict__ Kp, int kstride,
                                                  const u16* __restrict__ Vt,
                                                  u16* __restrict__ Op){
  __shared__ __align__(16) u16 Ks[64][72];     // [kv][d]
  __shared__ __align__(16) u16 Vs[64][72];     // [d][kv-tile]
  __shared__ __align__(16) u16 Pb[4][16][72];  // per-wave P [q][kv]
  int bh = blockIdx.x;
  int b = bh >> 3, h = bh & 7;
  int q0 = blockIdx.y * 128;
  int tid = threadIdx.x;
  int wv = tid >> 6, lane = tid & 63, l15 = lane & 15, quad = lane >> 4;
  const u16* Kb = Kp + (size_t)(b * 512) * kstride + h * 64;
  const u16* Vb = Vt + (size_t)bh * 64 * 512;
  s16x8 qb0[2], qb1[2];
  #pragma unroll
  for (int g = 0; g < 2; g++){
    const u16* Qb = Qp + (size_t)(b * 512 + q0 + wv * 32 + g * 16 + l15) * qstride + h * 64;
    qb0[g] = *(const s16x8*)(Qb + quad * 8);
    qb1[g] = *(const s16x8*)(Qb + 32 + quad * 8);
  }
  f32x4 o[2][4] = {};
  float m[2] = {-3e38f, -3e38f}, l[2] = {0.0f, 0.0f};
  int sr = tid >> 3, sc = (tid & 7) * 8;

  for (int kt = 0; kt < 512; kt += 64){
    __syncthreads();
    *(u16x8*)&Ks[sr][sc]      = *(const u16x8*)(Kb + (size_t)(kt + sr) * kstride + sc);
    *(u16x8*)&Ks[sr + 32][sc] = *(const u16x8*)(Kb + (size_t)(kt + sr + 32) * kstride + sc);
    *(u16x8*)&Vs[sr][sc]      = *(const u16x8*)(Vb + (size_t)sr * 512 + kt + sc);
    *(u16x8*)&Vs[sr + 32][sc] = *(const u16x8*)(Vb + (size_t)(sr + 32) * 512 + kt + sc);
    __syncthreads();
    #pragma unroll
    for (int g = 0; g < 2; g++){
      f32x4 st[4];
      #pragma unroll
      for (int t = 0; t < 4; t++){
        s16x8 ka0 = *(const s16x8*)&Ks[t * 16 + l15][quad * 8];
        s16x8 ka1 = *(const s16x8*)&Ks[t * 16 + l15][32 + quad * 8];
        f32x4 acc = {0,0,0,0};
        acc = __builtin_amdgcn_mfma_f32_16x16x32_bf16(ka0, qb0[g], acc, 0, 0, 0);
        acc = __builtin_amdgcn_mfma_f32_16x16x32_bf16(ka1, qb1[g], acc, 0, 0, 0);
        st[t] = acc * 0.125f;
      }
      float mx = st[0][0];
      #pragma unroll
      for (int t = 0; t < 4; t++)
        #pragma unroll
        for (int r = 0; r < 4; r++) mx = fmaxf(mx, st[t][r]);
      mx = fmaxf(mx, __shfl_xor(mx, 16));
      mx = fmaxf(mx, __shfl_xor(mx, 32));
      float mn = fmaxf(m[g], mx);
      float alpha = __expf(m[g] - mn);
      m[g] = mn;
      float rs = 0.0f;
      u16x4 pk[4];
      #pragma unroll
      for (int t = 0; t < 4; t++){
        #pragma unroll
        for (int r = 0; r < 4; r++){
          float p = __expf(st[t][r] - mn);
          rs += p;
          pk[t][r] = f2bf(p);
        }
      }
      rs += __shfl_xor(rs, 16);
      rs += __shfl_xor(rs, 32);
      l[g] = l[g] * alpha + rs;
      #pragma unroll
      for (int u = 0; u < 4; u++) o[g][u] *= alpha;
      #pragma unroll
      for (int t = 0; t < 4; t++)
        *(u16x4*)&Pb[wv][l15][t * 16 + quad * 4] = pk[t];
      s16x8 pb0 = *(const s16x8*)&Pb[wv][l15][quad * 8];
      s16x8 pb1 = *(const s16x8*)&Pb[wv][l15][32 + quad * 8];
      #pragma unroll
      for (int u = 0; u < 4; u++){
        s16x8 va0 = *(const s16x8*)&Vs[u * 16 + l15][quad * 8];
        s16x8 va1 = *(const s16x8*)&Vs[u * 16 + l15][32 + quad * 8];
        o[g][u] = __builtin_amdgcn_mfma_f32_16x16x32_bf16(va0, pb0, o[g][u], 0, 0, 0);
        o[g][u] = __builtin_amdgcn_mfma_f32_16x16x32_bf16(va1, pb1, o[g][u], 0, 0, 0);
      }
    }
  }
  #pragma unroll
  for (int g = 0; g < 2; g++){
    float invl = 1.0f / l[g];
    u16* ob = Op + (size_t)(b * 512 + q0 + wv * 32 + g * 16 + l15) * 512 + h * 64 + quad * 4;
    #pragma unroll
    for (int u = 0; u < 4; u++){
      u16x4 pk;
      pk[0] = f2bf(o[g][u][0] * invl);
      pk[1] = f2bf(o[g][u][1] * invl);
      pk[2] = f2bf(o[g][u][2] * invl);
      pk[3] = f2bf(o[g][u][3] * invl);
      *(u16x4*)(ob + u * 16) = pk;
    }
  }
}

// ---------------- forward-kinematics tail (fp32 out) ----------------
// 256 blocks x 64 threads: all CUs occupied; hardware sin/cos.
__global__ __launch_bounds__(64) void fk_kernel(const float* __restrict__ head, float* __restrict__ out){
  const int P[50] = {-1,0,1,2,3,1,5,6,1,
    4,9,10,11, 4,13,14,15, 4,17,18,19, 4,21,22,23, 4,25,26,27,
    7,29,30,31, 7,33,34,35, 7,37,38,39, 7,41,42,43, 7,45,46,47,
    8};
  int r = blockIdx.x * 64 + threadIdx.x;         // 16384 rows
  const float* o = head + (size_t)r * 102;
  float* ob = out + (size_t)r * 150;
  float g[50], px[50], py[50];
  g[0] = 0.0f; px[0] = o[100]; py[0] = o[101];
  ob[0] = px[0]; ob[1] = py[0]; ob[2] = 1.0f;
  #pragma unroll
  for (int j = 1; j < 50; j++){
    int p = P[j];
    float gc = g[p] + o[j];
    g[j] = gc;
    float sc = o[50 + j];
    float sn, cs;
    __sincosf(gc, &sn, &cs);
    px[j] = px[p] + cs * sc;
    py[j] = py[p] + sn * sc;
    ob[3 * j] = px[j]; ob[3 * j + 1] = py[j]; ob[3 * j + 2] = 1.0f;
  }
}

extern "C" void kernel_launch(void* const* d_in, const int* in_sizes, int n_in,
                              void* d_out, int out_size, void* d_ws, size_t ws_size,
                              hipStream_t stream){
  (void)in_sizes; (void)n_in; (void)out_size; (void)ws_size;
  const float* memory   = (const float*)d_in[0];
  const float* in_w     = (const float*)d_in[1];
  const float* in_b     = (const float*)d_in[2];
  const float* conv_w   = (const float*)d_in[3];
  const float* conv_b   = (const float*)d_in[4];
  const float* qemb     = (const float*)d_in[5];
  const float* sa_in_w  = (const float*)d_in[6];
  const float* sa_in_b  = (const float*)d_in[7];
  const float* sa_out_w = (const float*)d_in[8];
  const float* sa_out_b = (const float*)d_in[9];
  const float* ca_in_w  = (const float*)d_in[10];
  const float* ca_in_b  = (const float*)d_in[11];
  const float* ca_out_w = (const float*)d_in[12];
  const float* ca_out_b = (const float*)d_in[13];
  const float* ln1_g    = (const float*)d_in[14];
  const float* ln1_b    = (const float*)d_in[15];
  const float* ln2_g    = (const float*)d_in[16];
  const float* ln2_b    = (const float*)d_in[17];
  const float* ln3_g    = (const float*)d_in[18];
  const float* ln3_b    = (const float*)d_in[19];
  const float* ff1_w    = (const float*)d_in[20];
  const float* ff1_b    = (const float*)d_in[21];
  const float* ff2_w    = (const float*)d_in[22];
  const float* ff2_b    = (const float*)d_in[23];
  const float* out_w    = (const float*)d_in[24];
  const float* out_b    = (const float*)d_in[25];

  char* ws = (char*)d_ws;
  float* pe    = (float*)(ws);                    //  1,048,576 B
  float* x     = (float*)(ws + 1048576);          // 33,554,432 B (fp32 residual)
  u16*   memb  = (u16*)  (ws + 34603008);         // 16,777,216 B
  u16*   hb    = (u16*)  (ws + 51380224);         // 16,777,216 B (LN out / attn out)
  u16*   wp    = (u16*)  (ws + 68157440);         // 36,280,320 B bf16 weight pool
  char*  big   =          ws + 104857600;         // 50,331,648 B phase-shared (end 155,189,248)

  // weight pool offsets (elements)
  u16* w_in    = wp + 0;          // 262,144
  u16* w_convt = wp + 262144;     // 1,048,576
  u16* w_sain  = wp + 1310720;    // 3,145,728
  u16* w_saout = wp + 4456448;    // 1,048,576
  u16* w_cain  = wp + 5505024;    // 3,145,728
  u16* w_caout = wp + 8650752;    // 1,048,576
  u16* w_ff1   = wp + 9699328;    // 4,194,304
  u16* w_ff2   = wp + 13893632;   // 4,194,304
  u16* w_out   = wp + 18087936;   // 52,224

  // big-region phase views
  u16* mcast   = (u16*)big;                       // 4096x512 bf16 (conv phase)
  u16* mb      = (u16*)(big + 4194304);           // 4096x512
  u16* convlin = (u16*)(big + 8388608);           // 4096x2048
  u16* qkv2 = (u16*)big;                          // 16384x1024 (SA: Q|K)
  u16* qb   = (u16*)big;                          // 16384x512  (CA: Q)
  u16* kvbK = (u16*)(big + 16777216);             // 16384x512  (CA: K)
  u16* vtg  = (u16*)(big + 33554432);             // 256x64x512 V^T
  u16* f1b  = (u16*)big;                          // 8192x2048  (FF phase, half rows)
  float* head = (float*)big;                      // 16384x102 fp32 (head phase)

  dim3 blk(256);
  // ---- prologue: pe + fused casts ----
  pe_kernel<<<1024, blk, 0, stream>>>(pe);
  {
    C9 a;
    const float* srcs[9] = {in_w, memory, sa_in_w, sa_out_w, ca_in_w, ca_out_w, ff1_w, ff2_w, out_w};
    u16* dsts[9] = {w_in, mcast, w_sain, w_saout, w_cain, w_caout, w_ff1, w_ff2, w_out};
    // sizes in 4-ELEMENT units (total elements / 4)
    int sz4[9] = {65536, 524288, 786432, 262144, 786432, 262144, 1048576, 1048576, 13056};
    int cum = 0;
    for (int i = 0; i < 9; i++){ a.s[i] = srcs[i]; a.d[i] = dsts[i]; a.e[i] = cum; cum += sz4[i]; }
    a.e[9] = cum;   // 4,797,184
    cast_all<<<(cum + 255) / 256, blk, 0, stream>>>(a);
  }
  convw_t_kernel<<<4096, blk, 0, stream>>>(conv_w, w_convt);
  initx_kernel<<<32768, blk, 0, stream>>>(qemb, pe, x);
  // m = memory @ in_proj_w^T + b     (4096 x 512), nm=32 nn=4
  gemm_lds<EPI_BF16><<<dim3(128, 1, 1),  blk, 0, stream>>>(mcast, 512, w_in, 512, in_b, mb, nullptr, 512, 512, 512, nullptr, 0, 32);
  // convlin = m @ convwt^T           (4096 x 2048), nm=32 nn=16
  gemm_lds<EPI_BF16><<<dim3(512, 1, 1), blk, 0, stream>>>(mb, 512, w_convt, 512, nullptr, convlin, nullptr, 2048, 2048, 512, nullptr, 0, 32);
  mem_kernel<<<32768, blk, 0, stream>>>(convlin, conv_b, pe, memb);

  for (int l = 0; l < 4; l++){
    // ---- self attention ----
    ln_kernel<<<4096, blk, 0, stream>>>(x, ln1_g + l*512, ln1_b + l*512, hb);
    gemm_lds<EPI_QKVT><<<dim3(1536, 1, 1), blk, 0, stream>>>(hb, 512, w_sain + (size_t)l*786432, 512,
                                                             sa_in_b + l*1536, qkv2, nullptr, 1024, 1536, 512, vtg, 1024, 128);
    attn_mfma2<<<dim3(256, 4), blk, 0, stream>>>(qkv2, 1024, qkv2 + 512, 1024, vtg, hb);
    gemm_lds<EPI_RES><<<dim3(512, 1, 1), blk, 0, stream>>>(hb, 512, w_saout + (size_t)l*262144, 512,
                                                           sa_out_b + l*512, nullptr, x, 512, 512, 512, nullptr, 0, 128);
    // ---- cross attention ----
    ln_kernel<<<4096, blk, 0, stream>>>(x, ln2_g + l*512, ln2_b + l*512, hb);
    gemm_lds<EPI_BF16><<<dim3(512, 1, 1),  blk, 0, stream>>>(hb, 512, w_cain + (size_t)l*786432, 512,
                                                             ca_in_b + l*1536, qb, nullptr, 512, 512, 512, nullptr, 0, 128);
    gemm_lds<EPI_QKVT><<<dim3(1024, 1, 1), blk, 0, stream>>>(memb, 512, w_cain + (size_t)l*786432 + 262144, 512,
                                                             ca_in_b + l*1536 + 512, kvbK, nullptr, 512, 1024, 512, vtg, 512, 128);
    attn_mfma2<<<dim3(256, 4), blk, 0, stream>>>(qb, 512, kvbK, 512, vtg, hb);
    gemm_lds<EPI_RES><<<dim3(512, 1, 1), blk, 0, stream>>>(hb, 512, w_caout + (size_t)l*262144, 512,
                                                           ca_out_b + l*512, nullptr, x, 512, 512, 512, nullptr, 0, 128);
    // ---- feed forward (two row-halves to bound scratch) ----
    ln_kernel<<<4096, blk, 0, stream>>>(x, ln3_g + l*512, ln3_b + l*512, hb);
    for (int h2 = 0; h2 < 2; h2++){
      size_t ro = (size_t)h2 * 8192;
      gemm_lds<EPI_GELU><<<dim3(1024, 1, 1), blk, 0, stream>>>(hb + ro*512, 512, w_ff1 + (size_t)l*1048576, 512,
                                                               ff1_b + l*2048, f1b, nullptr, 2048, 2048, 512, nullptr, 0, 64);
      gemm_lds<EPI_RES><<<dim3(256, 1, 2), blk, 0, stream>>>(f1b, 2048, w_ff2 + (size_t)l*1048576, 2048,
                                                             ff2_b + l*512, nullptr, x + ro*512, 512, 512, 2048, nullptr, 0, 64);
    }
  }
  cast_kernel<<<32768, blk, 0, stream>>>(x, hb);
  gemm_bt<EPI_F32><<<dim3(256, 2), blk, 0, stream>>>(hb, 512, w_out, 512, out_b, nullptr, head, 102, 102, 512);
  fk_kernel<<<256, dim3(64), 0, stream>>>(head, (float*)d_out);
}